// Round 12
// baseline (509.799 us; speedup 1.0000x reference)
//
#include <hip/hip_runtime.h>

#define D 256
#define NPTS 1024
#define H 4
#define LNUM 6

static constexpr size_t SL = (size_t)D * NPTS;  // 262144 elements

typedef __attribute__((ext_vector_type(8))) short bf16x8;
typedef __attribute__((ext_vector_type(4))) float f32x4;

__device__ __forceinline__ unsigned f2bf(float f) {  // RNE round to bf16 bits
  unsigned u = __float_as_uint(f);
  return (u + 0x7FFFu + ((u >> 16) & 1u)) >> 16;
}
__device__ __forceinline__ unsigned pack2(float a, float b) {
  return f2bf(a) | (f2bf(b) << 16);
}
__device__ __forceinline__ float bf2f(unsigned u) {
  return __uint_as_float(u << 16);
}
// XOR swizzle for [rows][64] bf16 LDS tiles (128 B rows): conflict-optimal b128
__device__ __forceinline__ int swz(int row, int byteInRow) {
  return row * 128 + (byteInRow ^ ((row & 7) << 4));
}

// ------------------------------------------------------------- MFMA GEMM ----
// Out[n][m] = sum_k X'[n][k]*W[m][k] + bias[m], X' = X (k<split) / X2 (k>=split).
// 128x128 block tile, 4 waves x 64x64 quadrant (wr=wid>>1, wc=wid&1).
// Direct global->LDS staging, 2 barriers/K-step (round-10 lesson: NO reg-staged
// dbuf). Epilogue: direct global stores with lane-pair shfl packing (no LDS).
// mode 0: bf16 out [n][m]. mode 1: fp32 out. mode 2: bf16 out transposed [m][n].
// qkv=1: z%3==2 -> mode 2, os=1024 (V); z%3==0 -> output scaled by 0.125 (Q).
struct MMArgs {
  const unsigned short* X[18];
  const unsigned short* X2[18];
  const unsigned short* W[18];
  const float* B[18];
  void* O[18];
};

template <bool RELU>
__global__ __launch_bounds__(256) void mm_bf16(MMArgs a, int K, int xs, int os,
                                               int mode0, int qkv, int split) {
  const int z = blockIdx.z;
  const unsigned short* __restrict__ X = a.X[z];
  const unsigned short* __restrict__ X2 = a.X2[z];
  const unsigned short* __restrict__ W = a.W[z];
  const float* __restrict__ Bb = a.B[z];

  int mode = mode0, osz = os;
  if (qkv && (z % 3 == 2)) { mode = 2; osz = 1024; }
  const float osc = (qkv && (z % 3 == 0)) ? 0.125f : 1.0f;  // Q pre-scale

  __shared__ char sm[32768];  // A tile 16K | B tile 16K (single buffer)
  char* smA = sm;
  char* smB = sm + 16384;

  const int tid = threadIdx.x;
  const int n0 = blockIdx.x * 128, m0 = blockIdx.y * 128;
  const int lane = tid & 63, wid = tid >> 6;
  const int wr = wid >> 1, wc = wid & 1;
  const int lr = lane & 15, lk = lane >> 4;
  const int kh = lk * 16;

  // staging: thread t -> row t>>1 (0..127) of both A and B, chunks (t&1)*4..+3
  const int srow = tid >> 1, sc4 = (tid & 1) * 4;

  f32x4 acc[4][4] = {};

  for (int k0 = 0; k0 < K; k0 += 64) {
#pragma unroll
    for (int j = 0; j < 4; ++j) {
      const int ck = sc4 + j;
      const int ke = k0 + ck * 8;
      int kx = ke;
      const unsigned short* xsrc = X;
      if (split && kx >= split) { xsrc = X2; kx -= split; }
      *(float4*)(smA + swz(srow, ck * 16)) =
          *(const float4*)(xsrc + (size_t)(n0 + srow) * xs + kx);
      *(float4*)(smB + swz(srow, ck * 16)) =
          *(const float4*)(W + (size_t)(m0 + srow) * K + ke);
    }
    __syncthreads();

    bf16x8 af[4][2];
#pragma unroll
    for (int ri = 0; ri < 4; ++ri) {
      const int ar = wr * 64 + ri * 16 + lr;
      af[ri][0] = *(const bf16x8*)(smA + swz(ar, kh));
      af[ri][1] = *(const bf16x8*)(smA + swz(ar, 64 + kh));
    }
#pragma unroll
    for (int ci = 0; ci < 4; ++ci) {
      const int br = wc * 64 + ci * 16 + lr;
      const bf16x8 b0 = *(const bf16x8*)(smB + swz(br, kh));
      const bf16x8 b1 = *(const bf16x8*)(smB + swz(br, 64 + kh));
#pragma unroll
      for (int ri = 0; ri < 4; ++ri) {
        acc[ri][ci] = __builtin_amdgcn_mfma_f32_16x16x32_bf16(af[ri][0], b0, acc[ri][ci], 0, 0, 0);
        acc[ri][ci] = __builtin_amdgcn_mfma_f32_16x16x32_bf16(af[ri][1], b1, acc[ri][ci], 0, 0, 0);
      }
    }
    __syncthreads();
  }

  // epilogue: bias (+relu/scale), direct stores with lane-pair packing.
  // acc[ri][ci][r]: row = wr*64+ri*16+lk*4+r, col = wc*64+ci*16+lr.
#pragma unroll
  for (int ci = 0; ci < 4; ++ci) {
    const int col = wc * 64 + ci * 16 + lr;
    const float bs = Bb[m0 + col];
#pragma unroll
    for (int ri = 0; ri < 4; ++ri) {
      const int rowb = wr * 64 + ri * 16 + lk * 4;
      float v[4];
#pragma unroll
      for (int r = 0; r < 4; ++r) {
        float t = (acc[ri][ci][r] + bs) * osc;
        if (RELU) t = fmaxf(t, 0.f);
        v[r] = t;
      }
      if (mode == 2) {
        // transposed: out[m=col][n=row..row+3]; lane-local, uint2 (4 bf16)
        uint2 u;
        u.x = pack2(v[0], v[1]);
        u.y = pack2(v[2], v[3]);
        *(uint2*)((unsigned short*)a.O[z] + (size_t)(m0 + col) * osz + n0 + rowb) = u;
      } else if (mode == 0) {
        // [n][m] bf16: pack 4 cols via shfl_xor 1,2 -> quarter-lane uint2
#pragma unroll
        for (int r = 0; r < 4; ++r) {
          const float o1 = __shfl_xor(v[r], 1);
          const unsigned p01 = pack2(v[r], o1);
          const unsigned p23 = __shfl_xor((int)p01, 2);
          if ((lane & 3) == 0) {
            uint2 u;
            u.x = p01;
            u.y = (unsigned)p23;
            *(uint2*)((unsigned short*)a.O[z] + (size_t)(n0 + rowb + r) * osz + m0 + col) = u;
          }
        }
      } else {
        // fp32 [n][m]: pair cols via shfl_xor 1 -> even-lane float2
#pragma unroll
        for (int r = 0; r < 4; ++r) {
          const float o1 = __shfl_xor(v[r], 1);
          if (!(lane & 1)) {
            float2 u;
            u.x = v[r];
            u.y = o1;
            *(float2*)((float*)a.O[z] + (size_t)(n0 + rowb + r) * osz + m0 + col) = u;
          }
        }
      }
    }
  }
}

// ------------------------------------------------- split-K MFMA attention ----
// Block: 64 q x 1 head x 1 kt-chunk (256 kt), 256 threads (4 waves).
// SWAPPED QK^T: S^T = mfma(A=K rows kt, B=Q rows q) -> col q = lane&15.
// Each lane owns ONE q with 16 kt values -> in-register softmax + 2 shfl_xor.
// Q pre-scaled by 0.125 at projection.
struct AttnArgs {
  const unsigned short* Q[6];
  const unsigned short* K[6];
  const unsigned short* V[6];
};

__global__ __launch_bounds__(256) void attn_split(AttnArgs a, unsigned short* part) {
  const int z = blockIdx.z;
  const int h = blockIdx.y >> 2, ck = blockIdx.y & 3;
  const int n0 = blockIdx.x * 64;
  const unsigned short* __restrict__ Qp = a.Q[z];
  const unsigned short* __restrict__ Kp = a.K[z];
  const unsigned short* __restrict__ Vp = a.V[z];

  __shared__ char sm[49152];
  char* smQ = sm;           // 8 KB
  char* smKb = sm + 8192;   // 2 x 8 KB double buffer
  char* smVb = sm + 24576;  // 2 x 8 KB
  char* smP = sm + 40960;   // 8 KB (P[q][kt], wave-private rows)

  const int tid = threadIdx.x;
  const int lane = tid & 63, wid = tid >> 6;
  const int srow = tid >> 2, skb = (tid & 3) * 16;  // 64 rows x 2 16B-chunks
  const int kb0 = ck * 256;

#pragma unroll
  for (int p = 0; p < 2; ++p) {
    const int b = skb + 64 * p;
    *(float4*)(smQ + swz(srow, b)) =
        *(const float4*)(Qp + (size_t)(n0 + srow) * 256 + h * 64 + (b >> 1));
    *(float4*)(smKb + swz(srow, b)) =
        *(const float4*)(Kp + (size_t)(kb0 + srow) * 256 + h * 64 + (b >> 1));
    *(float4*)(smVb + swz(srow, b)) =
        *(const float4*)(Vp + (size_t)(h * 64 + srow) * NPTS + kb0 + (b >> 1));
  }
  __syncthreads();

  const int kh = (lane >> 4) * 16;
  const int qr = wid * 16 + (lane & 15);  // this lane's q row (and P/A-frag row)
  const bf16x8 qb0 = *(const bf16x8*)(smQ + swz(qr, kh));
  const bf16x8 qb1 = *(const bf16x8*)(smQ + swz(qr, 64 + kh));

  f32x4 accO[4] = {{0.f, 0.f, 0.f, 0.f}, {0.f, 0.f, 0.f, 0.f},
                   {0.f, 0.f, 0.f, 0.f}, {0.f, 0.f, 0.f, 0.f}};
  float mrun = -1e30f, lrun = 0.f;  // per-lane scalars (q = qr)

  for (int t = 0; t < 4; ++t) {
    const int co = (t & 1) << 13;
    if (t < 3) {  // prefetch next tile into other buffer
      const int no = ((t + 1) & 1) << 13;
      const int kt = kb0 + (t + 1) * 64;
#pragma unroll
      for (int p = 0; p < 2; ++p) {
        const int b = skb + 64 * p;
        *(float4*)(smKb + no + swz(srow, b)) =
            *(const float4*)(Kp + (size_t)(kt + srow) * 256 + h * 64 + (b >> 1));
        *(float4*)(smVb + no + swz(srow, b)) =
            *(const float4*)(Vp + (size_t)(h * 64 + srow) * NPTS + kt + (b >> 1));
      }
    }

    // S^T tile: s[c][r] = S[q = qr][kt = c*16 + (lane>>4)*4 + r]
    f32x4 s[4];
#pragma unroll
    for (int c = 0; c < 4; ++c) {
      const int br = c * 16 + (lane & 15);
      const bf16x8 kf0 = *(const bf16x8*)(smKb + co + swz(br, kh));
      const bf16x8 kf1 = *(const bf16x8*)(smKb + co + swz(br, 64 + kh));
      f32x4 tt = {0.f, 0.f, 0.f, 0.f};
      tt = __builtin_amdgcn_mfma_f32_16x16x32_bf16(kf0, qb0, tt, 0, 0, 0);
      tt = __builtin_amdgcn_mfma_f32_16x16x32_bf16(kf1, qb1, tt, 0, 0, 0);
      s[c] = tt;
    }

    // in-register online softmax (16 values/lane, all same q)
    float mx = s[0][0];
#pragma unroll
    for (int c = 0; c < 4; ++c)
#pragma unroll
      for (int r = 0; r < 4; ++r) mx = fmaxf(mx, s[c][r]);
    mx = fmaxf(mx, __shfl_xor(mx, 16));
    mx = fmaxf(mx, __shfl_xor(mx, 32));
    const float mn = fmaxf(mrun, mx);
    const float corr = __expf(mrun - mn);
    mrun = mn;
    float ps = 0.f;
#pragma unroll
    for (int c = 0; c < 4; ++c)
#pragma unroll
      for (int r = 0; r < 4; ++r) {
        const float e = __expf(s[c][r] - mn);
        s[c][r] = e;
        ps += e;
      }
    ps += __shfl_xor(ps, 16);
    ps += __shfl_xor(ps, 32);
    lrun = lrun * corr + ps;

    // P write: lane-local consecutive kt -> uint2, no shuffles
#pragma unroll
    for (int c = 0; c < 4; ++c) {
      uint2 u;
      u.x = pack2(s[c][0], s[c][1]);
      u.y = pack2(s[c][2], s[c][3]);
      *(uint2*)(smP + swz(qr, c * 32 + (lane >> 4) * 8)) = u;
    }

    // rescale accO rows (corr broadcast from lanes 0..15 of this wave)
#pragma unroll
    for (int r = 0; r < 4; ++r) {
      const float cr = __shfl(corr, ((lane >> 4) & 3) * 4 + r);
#pragma unroll
      for (int c = 0; c < 4; ++c) accO[c][r] *= cr;
    }

    // O += P V (A = P rows q, B = V^T rows d, k = kt); P rows wave-private
    const bf16x8 pa0 = *(const bf16x8*)(smP + swz(qr, kh));
    const bf16x8 pa1 = *(const bf16x8*)(smP + swz(qr, 64 + kh));
#pragma unroll
    for (int c = 0; c < 4; ++c) {
      const int vr = c * 16 + (lane & 15);
      const bf16x8 vb0 = *(const bf16x8*)(smVb + co + swz(vr, kh));
      const bf16x8 vb1 = *(const bf16x8*)(smVb + co + swz(vr, 64 + kh));
      accO[c] = __builtin_amdgcn_mfma_f32_16x16x32_bf16(pa0, vb0, accO[c], 0, 0, 0);
      accO[c] = __builtin_amdgcn_mfma_f32_16x16x32_bf16(pa1, vb1, accO[c], 0, 0, 0);
    }
    __syncthreads();  // buf[cur] reads done; prefetch of buf[nxt] visible
  }

  // partial record: O bf16[64][64] | m f32[64] | l f32[64]
  char* rec = (char*)part +
              (size_t)((((z * 4 + h) * 16 + blockIdx.x) * 4 + ck)) * 8704;
#pragma unroll
  for (int c = 0; c < 4; ++c)
#pragma unroll
    for (int r = 0; r < 4; ++r) {
      const float o0 = accO[c][r];
      const float o1 = __shfl_xor(o0, 1);
      if (!(lane & 1)) {
        const int row = wid * 16 + (lane >> 4) * 4 + r;
        const int col = c * 16 + (lane & 15);
        *(unsigned*)(rec + row * 128 + col * 2) = pack2(o0, o1);
      }
    }
  if (lane < 16) {
    *(float*)(rec + 8192 + (wid * 16 + lane) * 4) = mrun;
    *(float*)(rec + 8448 + (wid * 16 + lane) * 4) = lrun;
  }
}

// combine 4 kt-chunk partials -> O bf16 [n][256] head-grouped
struct CmbArgs {
  unsigned short* O[6];
};

__global__ __launch_bounds__(256) void attn_combine(CmbArgs a,
                                                    const unsigned short* part) {
  const int z = blockIdx.z, h = blockIdx.y, qb = blockIdx.x;
  const int tid = threadIdx.x;
  const int q = tid >> 2, t4 = tid & 3;
  const char* base = (const char*)part + (size_t)(((z * 4 + h) * 16 + qb) * 4) * 8704;

  float m[4], l[4];
#pragma unroll
  for (int i = 0; i < 4; ++i) {
    m[i] = *(const float*)(base + i * 8704 + 8192 + q * 4);
    l[i] = *(const float*)(base + i * 8704 + 8448 + q * 4);
  }
  const float M = fmaxf(fmaxf(m[0], m[1]), fmaxf(m[2], m[3]));
  float w[4], L = 0.f;
#pragma unroll
  for (int i = 0; i < 4; ++i) { w[i] = __expf(m[i] - M); L += w[i] * l[i]; }
  const float invL = 1.f / L;

  float o[16] = {};
#pragma unroll
  for (int i = 0; i < 4; ++i) {
    const char* Or = base + i * 8704 + q * 128 + t4 * 32;
    unsigned ua[8];
    *(uint4*)ua = *(const uint4*)Or;
    *(uint4*)(ua + 4) = *(const uint4*)(Or + 16);
#pragma unroll
    for (int j = 0; j < 8; ++j) {
      o[2 * j] += w[i] * bf2f(ua[j] & 0xFFFFu);
      o[2 * j + 1] += w[i] * bf2f(ua[j] >> 16);
    }
  }
  unsigned ou[8];
#pragma unroll
  for (int j = 0; j < 8; ++j) ou[j] = pack2(o[2 * j] * invL, o[2 * j + 1] * invL);
  unsigned short* Op = a.O[z] + (size_t)(qb * 64 + q) * 256 + h * 64 + t4 * 16;
  *(uint4*)Op = *(uint4*)ou;
  *(uint4*)(Op + 8) = *(uint4*)(ou + 4);
}

// ------------------------------------------------------ residual + LN ------
struct LnArgs {
  float* x[4];
  unsigned short* xb[4];
  const float* da[4];
  const float* db[4];
  const float* g[4];
  const float* b[4];
};

__global__ __launch_bounds__(256) void ln_rows(LnArgs a) {
  const int z = blockIdx.z;
  float* __restrict__ x = a.x[z];
  unsigned short* __restrict__ xb = a.xb[z];
  const float* __restrict__ da = a.da[z];
  const float* __restrict__ db = a.db[z];
  const float* __restrict__ g = a.g[z];
  const float* __restrict__ b = a.b[z];

  const int lane = threadIdx.x & 63, wid = threadIdx.x >> 6;
  const int n = blockIdx.x * 4 + wid;
  const size_t off = (size_t)n * 256 + lane * 4;

  float4 v = *(const float4*)(x + off);
  if (da) {
    const float4 w = *(const float4*)(da + off);
    v.x += w.x; v.y += w.y; v.z += w.z; v.w += w.w;
  }
  if (db) {
    const float4 w = *(const float4*)(db + off);
    v.x += w.x; v.y += w.y; v.z += w.z; v.w += w.w;
  }
  float s = v.x + v.y + v.z + v.w;
  float q = v.x * v.x + v.y * v.y + v.z * v.z + v.w * v.w;
#pragma unroll
  for (int o = 1; o < 64; o <<= 1) {
    s += __shfl_xor(s, o);
    q += __shfl_xor(q, o);
  }
  const float mu = s * (1.f / 256.f);
  const float var = q * (1.f / 256.f) - mu * mu;
  const float inv = rsqrtf(var + 1e-5f);
  const float4 gv = *(const float4*)(g + lane * 4);
  const float4 bv = *(const float4*)(b + lane * 4);
  float4 o;
  o.x = (v.x - mu) * inv * gv.x + bv.x;
  o.y = (v.y - mu) * inv * gv.y + bv.y;
  o.z = (v.z - mu) * inv * gv.z + bv.z;
  o.w = (v.w - mu) * inv * gv.w + bv.w;
  *(float4*)(x + off) = o;
  uint2 pk = {pack2(o.x, o.y), pack2(o.z, o.w)};
  *(uint2*)(xb + off) = pk;
}

// -------------------------------------------------------- small helpers ----
struct TrArgs {
  const float* s[4];
  float* d[4];
  unsigned short* db[4];
};
__global__ __launch_bounds__(256) void tr_init(TrArgs a) {  // [c][n] -> [n][c] + bf16
  const int z = blockIdx.z;
  const int n0 = blockIdx.x * 64, c0 = blockIdx.y * 64;
  __shared__ float T[64][65];
  const int tid = threadIdx.x;
#pragma unroll
  for (int p = 0; p < 4; ++p) {
    const int row = (tid >> 4) + 16 * p;
    const int col4 = (tid & 15) * 4;
    const float4 v = *(const float4*)(a.s[z] + (size_t)(c0 + row) * NPTS + n0 + col4);
    T[row][col4] = v.x; T[row][col4 + 1] = v.y; T[row][col4 + 2] = v.z; T[row][col4 + 3] = v.w;
  }
  __syncthreads();
#pragma unroll
  for (int p = 0; p < 4; ++p) {
    const int nr = (tid >> 4) + 16 * p;
    const int c4 = (tid & 15) * 4;
    float4 v;
    v.x = T[c4][nr]; v.y = T[c4 + 1][nr]; v.z = T[c4 + 2][nr]; v.w = T[c4 + 3][nr];
    *(float4*)(a.d[z] + (size_t)(n0 + nr) * 256 + c0 + c4) = v;
    uint2 pk = {pack2(v.x, v.y), pack2(v.z, v.w)};
    *(uint2*)(a.db[z] + (size_t)(n0 + nr) * 256 + c0 + c4) = pk;
  }
}

// weight prep. pair pi = br*5+i (layers 0..4).
// arena per pair (ushort): WQ'(64K) WK'(64K) WV'(64K) MWt(64K) W1'(256K) W2'(128K)
__global__ __launch_bounds__(256) void wp_qkv(const float* __restrict__ pw,
                                              const float* __restrict__ pb,
                                              unsigned short* __restrict__ wbf,
                                              float* __restrict__ pbias) {
  const int z = blockIdx.z;  // 45 = 15 pairs x 3 j
  const int pi = z / 3, j = z % 3;
  const int br = pi / 5, i = pi % 5;
  const float* src = pw + (((size_t)br * LNUM + i) * 3 + j) * 65536;
  unsigned short* dst = wbf + (size_t)pi * 655360 + (size_t)j * 65536;
  const int t = blockIdx.x * 256 + threadIdx.x;  // 16384
  const int mp = t >> 6, k4 = (t & 63) * 4;
  const int m = (mp & 63) * 4 + (mp >> 6);  // orig channel of head-grouped mp
  const float4 v = *(const float4*)(src + (size_t)m * 256 + k4);
  uint2 pk = {pack2(v.x, v.y), pack2(v.z, v.w)};
  *(uint2*)(dst + (size_t)mp * 256 + k4) = pk;
  if (blockIdx.x == 0) {
    const float* sb = pb + (((size_t)br * LNUM + i) * 3 + j) * 256;
    const int mb = threadIdx.x;
    pbias[(size_t)z * 256 + mb] = sb[(mb & 63) * 4 + (mb >> 6)];
  }
}

// MWt[c'][m] = merge_w[m][orig(c')]  (transposed, O-channel head-grouped rows)
__global__ __launch_bounds__(256) void wp_mwt(const float* __restrict__ mw,
                                              unsigned short* __restrict__ wbf,
                                              float* __restrict__ zb) {
  const int pi = blockIdx.z;
  const int br = pi / 5, i = pi % 5;
  const float* src = mw + ((size_t)br * LNUM + i) * 65536;
  unsigned short* dst = wbf + (size_t)pi * 655360 + 196608;
  const int t = blockIdx.x * 256 + threadIdx.x;  // 16384
  const int cp = t >> 6, m4 = (t & 63) * 4;
  const int c = (cp & 63) * 4 + (cp >> 6);  // orig col of head-grouped cp
  float v[4];
#pragma unroll
  for (int u = 0; u < 4; ++u) v[u] = src[(size_t)(m4 + u) * 256 + c];
  uint2 pk = {pack2(v[0], v[1]), pack2(v[2], v[3])};
  *(uint2*)(dst + (size_t)cp * 256 + m4) = pk;
  if (blockIdx.x == 0 && pi == 0) zb[threadIdx.x] = 0.f;
}

// W1 cast [512][512]; also emit right half (cols 256..511) to whi temp
__global__ __launch_bounds__(256) void wp_c1(const float* __restrict__ w1,
                                             unsigned short* __restrict__ wbf,
                                             unsigned short* __restrict__ whi) {
  const int pi = blockIdx.z;
  const int br = pi / 5, i = pi % 5;
  const float* src = w1 + ((size_t)br * LNUM + i) * 262144;
  unsigned short* dst = wbf + (size_t)pi * 655360 + 262144;
  const int t = blockIdx.x * 256 + threadIdx.x;  // 65536
  const float4 v = *(const float4*)(src + (size_t)t * 4);
  uint2 pk = {pack2(v.x, v.y), pack2(v.z, v.w)};
  *(uint2*)(dst + (size_t)t * 4) = pk;
  const int idx = t * 4, row = idx >> 9, col = idx & 511;
  if (col >= 256)
    *(uint2*)(whi + (size_t)pi * 131072 + (size_t)row * 256 + (col - 256)) = pk;
}

__global__ __launch_bounds__(256) void wp_c2(const float* __restrict__ w2,
                                             unsigned short* __restrict__ wbf) {
  const int pi = blockIdx.z;
  const int br = pi / 5, i = pi % 5;
  const float* src = w2 + ((size_t)br * LNUM + i) * 131072;
  unsigned short* dst = wbf + (size_t)pi * 655360 + 524288;
  const int t = blockIdx.x * 256 + threadIdx.x;  // 32768
  const float4 v = *(const float4*)(src + (size_t)t * 4);
  uint2 pk = {pack2(v.x, v.y), pack2(v.z, v.w)};
  *(uint2*)(dst + (size_t)t * 4) = pk;
}

// b1'[o] = b1[o] + sum_m W1_hi[o][m] * merge_b[m]   (fp32, per pair)
__global__ __launch_bounds__(256) void b1fold(const float* __restrict__ w1,
                                              const float* __restrict__ mb,
                                              const float* __restrict__ b1,
                                              float* __restrict__ out) {
  const int pi = blockIdx.z;
  const int br = pi / 5, i = pi % 5;
  const float* Wp = w1 + ((size_t)br * LNUM + i) * 262144;
  const float* Bp = mb + ((size_t)br * LNUM + i) * 256;
  const float* b1s = b1 + ((size_t)br * LNUM + i) * 512;
  __shared__ float mbs[256];
  mbs[threadIdx.x] = Bp[threadIdx.x];
  __syncthreads();
  for (int o = threadIdx.x; o < 512; o += 256) {
    float s = b1s[o];
    const float* Wr = Wp + (size_t)o * 512 + 256;
#pragma unroll 4
    for (int m = 0; m < 256; ++m) s = fmaf(Wr[m], mbs[m], s);
    out[(size_t)pi * 512 + o] = s;
  }
}

// ----------------------------------------------------- final (layer 5) ----
__device__ __forceinline__ float block_reduce_sum(float v) {
  __shared__ float smr[4];
  const int lane = threadIdx.x & 63, wid = threadIdx.x >> 6;
#pragma unroll
  for (int off = 32; off; off >>= 1) v += __shfl_xor(v, off);
  if (lane == 0) smr[wid] = v;
  __syncthreads();
  if (threadIdx.x == 0) v = smr[0] + smr[1] + smr[2] + smr[3];
  return v;
}

__global__ __launch_bounds__(256) void cs1(const float* __restrict__ X,
                                           float* __restrict__ part) {
  const int r0 = blockIdx.x * 64;
  float acc = 0.f;
  for (int r = 0; r < 64; ++r) acc += X[(size_t)(r0 + r) * 256 + threadIdx.x];
  part[(size_t)blockIdx.x * 256 + threadIdx.x] = acc;
}
__global__ __launch_bounds__(256) void cs2(const float* __restrict__ part,
                                           float* __restrict__ s1) {
  float acc = 0.f;
  for (int b = 0; b < 16; ++b) acc += part[(size_t)b * 256 + threadIdx.x];
  s1[threadIdx.x] = acc;
}
__global__ __launch_bounds__(256) void matvec_qbar(const float* __restrict__ Wq,
                                                   const float* __restrict__ bq,
                                                   const float* __restrict__ s1,
                                                   float* __restrict__ qbar) {
  const int d = blockIdx.x, t = threadIdx.x;
  float s = Wq[(size_t)d * 256 + t] * s1[t];
  s = block_reduce_sum(s);
  if (t == 0) qbar[d] = s + (float)NPTS * bq[d];
}
__global__ __launch_bounds__(256) void matvec_u(const float* __restrict__ Wk,
                                                const float* __restrict__ bk,
                                                const float* __restrict__ qbar,
                                                float* __restrict__ u) {
  const int c = blockIdx.x, t = threadIdx.x;
  float s = (c < 256) ? (Wk[(size_t)t * 256 + c] * qbar[t]) : (bk[t] * qbar[t]);
  s = block_reduce_sum(s);
  if (t == 0) u[c] = s;
}

// unreachable column-OR: partial[b][t] = OR over 16 rows of uint word t
__global__ __launch_bounds__(256) void ur_or(const unsigned* __restrict__ U,
                                             unsigned* __restrict__ part) {
  const int b = blockIdx.x;  // 64 blocks
  unsigned o = 0;
  for (int r = 0; r < 16; ++r) o |= U[(size_t)(b * 16 + r) * 256 + threadIdx.x];
  part[(size_t)b * 256 + threadIdx.x] = o;
}

// out[m] = mask ? -1e9 : (u . d0[m,:] + u[256]) / 32768 ; wave per m
__global__ __launch_bounds__(256) void final2(const float* __restrict__ d0,
                                              const float* __restrict__ u,
                                              const unsigned* __restrict__ part,
                                              float* __restrict__ out) {
  const int lane = threadIdx.x & 63, wid = threadIdx.x >> 6;
  const int m = blockIdx.x * 4 + wid;
  const float4 v = *(const float4*)(d0 + (size_t)m * 256 + lane * 4);
  const float4 uu = *(const float4*)(u + lane * 4);
  float s = v.x * uu.x + v.y * uu.y + v.z * uu.z + v.w * uu.w;
  unsigned f = part[(size_t)lane * 256 + (m >> 2)];
  f = (f >> ((m & 3) * 8)) & 0xFFu;
#pragma unroll
  for (int o = 32; o; o >>= 1) {
    s += __shfl_xor(s, o);
    f |= (unsigned)__shfl_xor((int)f, o);
  }
  if (lane == 0) out[m] = f ? -1e9f : (s + u[256]) * (1.f / 32768.f);
}

// ---------------------------------------------------------------- host ----
extern "C" void kernel_launch(void* const* d_in, const int* in_sizes, int n_in,
                              void* d_out, int out_size, void* d_ws, size_t ws_size,
                              hipStream_t stream) {
  const float* desc[4] = {(const float*)d_in[0], (const float*)d_in[1],
                          (const float*)d_in[2], (const float*)d_in[3]};
  const unsigned char* unreach = (const unsigned char*)d_in[5];
  const float* proj_w = (const float*)d_in[8];
  const float* proj_b = (const float*)d_in[9];
  const float* merge_w = (const float*)d_in[10];
  const float* merge_b = (const float*)d_in[11];
  const float* mlp_w1 = (const float*)d_in[12];
  const float* mlp_b1 = (const float*)d_in[13];
  const float* mlp_w2 = (const float*)d_in[14];
  const float* mlp_b2 = (const float*)d_in[15];
  const float* norm_g = (const float*)d_in[16];
  const float* norm_b = (const float*)d_in[17];
  float* out = (float*)d_out;

  float* ws = (float*)d_ws;
  // floats: dbuf 4SL | dbf 2SL | delta 6SL | wbf 4915200 | smalls 40960
  //         | attnpart 3342336 | whi 983040 | sets (4SL ushort each)
  float* dbufF[4];
  for (int t = 0; t < 4; ++t) dbufF[t] = ws + (size_t)t * SL;
  unsigned short* dbfB[4];
  for (int t = 0; t < 4; ++t) dbfB[t] = (unsigned short*)(ws + 4 * SL) + (size_t)t * SL;
  float* deltaF[6];
  for (int p = 0; p < 6; ++p) deltaF[p] = ws + 6 * SL + (size_t)p * SL;
  unsigned short* wbf = (unsigned short*)(ws + 12 * SL);
  float* pbias = ws + 12 * SL + 4915200;          // 11520
  unsigned* urpart = (unsigned*)(pbias + 11520);  // 16384 uints
  float* cspart = pbias + 11520 + 16384;          // 4096
  float* s1 = cspart + 4096;
  float* qbar = s1 + 256;
  float* uvec = qbar + 256;                       // 257 (+pad)
  float* b1prime = uvec + 260;                    // 7680
  float* zbias = b1prime + 7680;                  // 256
  unsigned short* attnpart = (unsigned short*)(ws + 12 * SL + 4915200 + 40960);
  unsigned short* whi = attnpart + (size_t)2 * 3342336;  // 15 x 512 x 256 ushorts
  const size_t base_f = 12 * SL + 4915200 + 40960 + 3342336 + 983040;
  long long avail = (long long)(ws_size / 4) - (long long)base_f;
  const size_t SET_US = 4 * SL;  // ushorts per set: Q,K,V,O
  int nsets = (int)(avail / (long long)(SET_US / 2));
  if (nsets > 6) nsets = 6;
  if (nsets < 1) nsets = 1;
  unsigned short* usBase = (unsigned short*)(ws + base_f);
  auto setQ = [&](int p) { return usBase + (size_t)p * SET_US; };
  auto setK = [&](int p) { return usBase + (size_t)p * SET_US + SL; };
  auto setV = [&](int p) { return usBase + (size_t)p * SET_US + 2 * SL; };
  auto setO = [&](int p) { return usBase + (size_t)p * SET_US + 3 * SL; };
  auto setH1 = [&](int p) { return usBase + (size_t)p * SET_US; };  // overlays Q,K

  // ---- prologue: mask OR, weight prep, merge-fold, input transpose ----
  ur_or<<<dim3(64), 256, 0, stream>>>((const unsigned*)unreach, urpart);
  wp_qkv<<<dim3(64, 1, 45), 256, 0, stream>>>(proj_w, proj_b, wbf, pbias);
  wp_mwt<<<dim3(64, 1, 15), 256, 0, stream>>>(merge_w, wbf, zbias);
  wp_c1<<<dim3(256, 1, 15), 256, 0, stream>>>(mlp_w1, wbf, whi);
  wp_c2<<<dim3(128, 1, 15), 256, 0, stream>>>(mlp_w2, wbf);
  b1fold<<<dim3(1, 1, 15), 256, 0, stream>>>(mlp_w1, merge_b, mlp_b1, b1prime);
  {  // Wf = W1_hi x MWt -> right half of W1' (cols 256..511)
    MMArgs m{};
    for (int pi = 0; pi < 15; ++pi) {
      const unsigned short* xw = whi + (size_t)pi * 131072;
      m.X[pi] = xw; m.X2[pi] = xw;
      m.W[pi] = wbf + (size_t)pi * 655360 + 196608;
      m.B[pi] = zbias;
      m.O[pi] = wbf + (size_t)pi * 655360 + 262144 + 256;
    }
    mm_bf16<false><<<dim3(4, 2, 15), 256, 0, stream>>>(m, 256, 256, 512, 0, 0, 0);
  }
  {
    TrArgs ta{};
    for (int t = 0; t < 4; ++t) { ta.s[t] = desc[t]; ta.d[t] = dbufF[t]; ta.db[t] = dbfB[t]; }
    tr_init<<<dim3(16, 4, 4), 256, 0, stream>>>(ta);
  }

  static const int selfp[4][3] = {{0, 0, 0}, {0, 1, 1}, {1, 2, 2}, {2, 3, 3}};
  static const int crossp[6][3] = {{0, 0, 1}, {0, 1, 0}, {1, 2, 1},
                                   {1, 1, 2}, {2, 0, 3}, {2, 3, 0}};

  for (int i = 0; i < 5; ++i) {
    const bool cross = (i & 1);
    const int np = cross ? 6 : 4;
    const int(*props)[3] = cross ? crossp : selfp;

    for (int p0 = 0; p0 < np; p0 += nsets) {
      const int g = (np - p0 < nsets) ? (np - p0) : nsets;

      // fused q,k,v projections (z%3==2 -> V transposed; z%3==0 -> Q x0.125)
      {
        MMArgs m{};
        for (int p = 0; p < g; ++p) {
          const int br = props[p0 + p][0], xi = props[p0 + p][1], si = props[p0 + p][2];
          const int pi = br * 5 + i;
          unsigned short* wb = wbf + (size_t)pi * 655360;
          const unsigned short* xq = dbfB[xi];
          const unsigned short* xsv = dbfB[si];
          m.X[p * 3 + 0] = xq; m.X2[p * 3 + 0] = xq; m.W[p * 3 + 0] = wb;
          m.B[p * 3 + 0] = pbias + ((size_t)pi * 3 + 0) * 256; m.O[p * 3 + 0] = setQ(p);
          m.X[p * 3 + 1] = xsv; m.X2[p * 3 + 1] = xsv; m.W[p * 3 + 1] = wb + 65536;
          m.B[p * 3 + 1] = pbias + ((size_t)pi * 3 + 1) * 256; m.O[p * 3 + 1] = setK(p);
          m.X[p * 3 + 2] = xsv; m.X2[p * 3 + 2] = xsv; m.W[p * 3 + 2] = wb + 131072;
          m.B[p * 3 + 2] = pbias + ((size_t)pi * 3 + 2) * 256; m.O[p * 3 + 2] = setV(p);
        }
        mm_bf16<false><<<dim3(8, 2, 3 * g), 256, 0, stream>>>(m, 256, 256, 256, 0, 1, 0);
      }
      // attention: split-K partials then combine
      {
        AttnArgs aa{};
        for (int p = 0; p < g; ++p) {
          aa.Q[p] = setQ(p); aa.K[p] = setK(p); aa.V[p] = setV(p);
        }
        attn_split<<<dim3(16, 16, g), 256, 0, stream>>>(aa, attnpart);
        CmbArgs cc{};
        for (int p = 0; p < g; ++p) cc.O[p] = setO(p);
        attn_combine<<<dim3(16, 4, g), 256, 0, stream>>>(cc, attnpart);
      }
      // mlp1 (relu): K=512 dual-source (x | attnO), merge folded into W1'
      {
        MMArgs m{};
        for (int p = 0; p < g; ++p) {
          const int br = props[p0 + p][0], xi = props[p0 + p][1];
          const int pi = br * 5 + i;
          m.X[p] = dbfB[xi]; m.X2[p] = setO(p);
          m.W[p] = wbf + (size_t)pi * 655360 + 262144;
          m.B[p] = b1prime + (size_t)pi * 512; m.O[p] = setH1(p);
        }
        mm_bf16<true><<<dim3(8, 4, g), 256, 0, stream>>>(m, 512, 256, 512, 0, 0, 256);
      }
      // mlp2 -> delta (fp32)
      {
        MMArgs m{};
        for (int p = 0; p < g; ++p) {
          const int br = props[p0 + p][0];
          const int pi = br * 5 + i;
          m.X[p] = setH1(p); m.X2[p] = setH1(p);
          m.W[p] = wbf + (size_t)pi * 655360 + 524288;
          m.B[p] = mlp_b2 + ((size_t)br * LNUM + i) * 256; m.O[p] = deltaF[p0 + p];
        }
        mm_bf16<false><<<dim3(8, 2, g), 256, 0, stream>>>(m, 512, 512, 256, 1, 0, 0);
      }
    }

    // residual + LN (all four descriptors)
    {
      LnArgs la{};
      for (int t = 0; t < 4; ++t) {
        la.x[t] = dbufF[t]; la.xb[t] = dbfB[t];
        const float* da = nullptr;
        const float* db2 = nullptr;
        for (int p = 0; p < np; ++p)
          if (props[p][1] == t) {
            if (!da) da = deltaF[p];
            else db2 = deltaF[p];
          }
        la.da[t] = da; la.db[t] = db2;
        la.g[t] = norm_g + ((size_t)t * LNUM + i) * 256;
        la.b[t] = norm_b + ((size_t)t * LNUM + i) * 256;
      }
      ln_rows<<<dim3(256, 1, 4), 256, 0, stream>>>(la);
    }
  }

  // ---- layer 5 shortcut ----
  const float* Wq5 = proj_w + (((size_t)0 * LNUM + 5) * 3 + 0) * 65536;
  const float* bq5 = proj_b + (((size_t)0 * LNUM + 5) * 3 + 0) * 256;
  const float* Wk5 = proj_w + (((size_t)0 * LNUM + 5) * 3 + 1) * 65536;
  const float* bk5 = proj_b + (((size_t)0 * LNUM + 5) * 3 + 1) * 256;

  cs1<<<dim3(16), 256, 0, stream>>>(dbufF[1], cspart);
  cs2<<<dim3(1), 256, 0, stream>>>(cspart, s1);
  matvec_qbar<<<dim3(256), 256, 0, stream>>>(Wq5, bq5, s1, qbar);
  matvec_u<<<dim3(257), 256, 0, stream>>>(Wk5, bk5, qbar, uvec);
  final2<<<dim3(256), 256, 0, stream>>>(dbufF[0], uvec, urpart, out);

  (void)in_sizes; (void)n_in; (void)out_size;
}

// Round 14
// 336.233 us; speedup vs baseline: 1.5162x; 1.5162x over previous
//
#include <hip/hip_runtime.h>

#define D 256
#define NPTS 1024
#define H 4
#define LNUM 6

static constexpr size_t SL = (size_t)D * NPTS;  // 262144 elements

typedef __attribute__((ext_vector_type(8))) short bf16x8;
typedef __attribute__((ext_vector_type(4))) float f32x4;

__device__ __forceinline__ unsigned f2bf(float f) {  // RNE round to bf16 bits
  unsigned u = __float_as_uint(f);
  return (u + 0x7FFFu + ((u >> 16) & 1u)) >> 16;
}
__device__ __forceinline__ unsigned pack2(float a, float b) {
  return f2bf(a) | (f2bf(b) << 16);
}
__device__ __forceinline__ float bf2f(unsigned u) {
  return __uint_as_float(u << 16);
}
// XOR swizzle for [rows][64] bf16 LDS tiles (128 B rows): conflict-optimal b128
__device__ __forceinline__ int swz(int row, int byteInRow) {
  return row * 128 + (byteInRow ^ ((row & 7) << 4));
}

// ------------------------------------------------------------- MFMA GEMM ----
// Out[n][m] = sum_k X'[n][k]*W[m][k] + bias[m], X' = X (k<split) / X2 (k>=split).
// 64x64 tile, 2-barrier K-loop (round-9 known-good; rounds 10/12 restructures
// both regressed — do not change staging or epilogue structure).
// mode 0: bf16 out [n][m]. mode 1: fp32 out. mode 2: bf16 out transposed [m][n].
// qkv=1: z%3==2 -> mode 2, os=1024 (V); z%3==0 -> output scaled by 0.125 (Q).
struct MMArgs {
  const unsigned short* X[18];
  const unsigned short* X2[18];
  const unsigned short* W[18];
  const float* B[18];
  void* O[18];
};

template <bool RELU>
__global__ __launch_bounds__(256) void mm_bf16(MMArgs a, int K, int xs, int os,
                                               int mode0, int qkv, int split) {
  const int z = blockIdx.z;
  const unsigned short* __restrict__ X = a.X[z];
  const unsigned short* __restrict__ X2 = a.X2[z];
  const unsigned short* __restrict__ W = a.W[z];
  const float* __restrict__ Bb = a.B[z];

  int mode = mode0, osz = os;
  if (qkv && (z % 3 == 2)) { mode = 2; osz = 1024; }
  const float osc = (qkv && (z % 3 == 0)) ? 0.125f : 1.0f;  // Q pre-scale 1/sqrt(dh)

  __shared__ char sm[64 * 68 * 4];  // 16 KB staging; epilogue fp32 64x68
  char* smX = sm;
  char* smW = sm + 8192;

  const int tid = threadIdx.x;
  const int n0 = blockIdx.x * 64, m0 = blockIdx.y * 64;
  const int lane = tid & 63, wid = tid >> 6;

  f32x4 acc[4] = {{0.f, 0.f, 0.f, 0.f}, {0.f, 0.f, 0.f, 0.f},
                  {0.f, 0.f, 0.f, 0.f}, {0.f, 0.f, 0.f, 0.f}};

  const int srow = tid >> 3, skb = (tid & 7) * 16;  // staging: 16B per thread
  const int ar = wid * 16 + (lane & 15);            // A row (n-local)
  const int kh = (lane >> 4) * 16;                  // k-half byte offset

  for (int k0 = 0; k0 < K; k0 += 64) {
    const int kw = k0 + (skb >> 1);  // element col
    int kx = kw;
    const unsigned short* xsrc = X;
    if (split && kx >= split) { xsrc = X2; kx -= split; }
#pragma unroll
    for (int p = 0; p < 2; ++p) {
      const int row = srow + 32 * p;
      *(float4*)(smX + swz(row, skb)) =
          *(const float4*)(xsrc + (size_t)(n0 + row) * xs + kx);
      *(float4*)(smW + swz(row, skb)) =
          *(const float4*)(W + (size_t)(m0 + row) * K + kw);
    }
    __syncthreads();
    const bf16x8 a0 = *(const bf16x8*)(smX + swz(ar, kh));
    const bf16x8 a1 = *(const bf16x8*)(smX + swz(ar, 64 + kh));
#pragma unroll
    for (int c = 0; c < 4; ++c) {
      const int br = c * 16 + (lane & 15);
      const bf16x8 b0 = *(const bf16x8*)(smW + swz(br, kh));
      const bf16x8 b1 = *(const bf16x8*)(smW + swz(br, 64 + kh));
      acc[c] = __builtin_amdgcn_mfma_f32_16x16x32_bf16(a0, b0, acc[c], 0, 0, 0);
      acc[c] = __builtin_amdgcn_mfma_f32_16x16x32_bf16(a1, b1, acc[c], 0, 0, 0);
    }
    __syncthreads();
  }

  // epilogue via LDS fp32 tile [64 n][68]
  float(*eps)[68] = (float(*)[68])sm;
#pragma unroll
  for (int c = 0; c < 4; ++c) {
    const float bs = Bb[m0 + c * 16 + (lane & 15)];
#pragma unroll
    for (int r = 0; r < 4; ++r) {
      float v = (acc[c][r] + bs) * osc;
      if (RELU) v = fmaxf(v, 0.f);
      eps[wid * 16 + (lane >> 4) * 4 + r][c * 16 + (lane & 15)] = v;
    }
  }
  __syncthreads();

#pragma unroll
  for (int p = 0; p < 2; ++p) {
    const int row = srow + 32 * p;
    const int c0 = (tid & 7) * 8;
    if (mode == 0) {
      const float4 lo = *(const float4*)&eps[row][c0];
      const float4 hi = *(const float4*)&eps[row][c0 + 4];
      uint4 u = {pack2(lo.x, lo.y), pack2(lo.z, lo.w), pack2(hi.x, hi.y), pack2(hi.z, hi.w)};
      *(uint4*)((unsigned short*)a.O[z] + (size_t)(n0 + row) * osz + m0 + c0) = u;
    } else if (mode == 1) {
      float* O = (float*)a.O[z];
      *(float4*)(O + (size_t)(n0 + row) * osz + m0 + c0) = *(const float4*)&eps[row][c0];
      *(float4*)(O + (size_t)(n0 + row) * osz + m0 + c0 + 4) = *(const float4*)&eps[row][c0 + 4];
    } else {  // transposed: out row = m, cols = n
      float v[8];
#pragma unroll
      for (int j = 0; j < 8; ++j) v[j] = eps[c0 + j][row];
      uint4 u = {pack2(v[0], v[1]), pack2(v[2], v[3]), pack2(v[4], v[5]), pack2(v[6], v[7])};
      *(uint4*)((unsigned short*)a.O[z] + (size_t)(m0 + row) * osz + n0 + c0) = u;
    }
  }
}

// ------------------------------------------------- split-K MFMA attention ----
// Block: 64 q x 1 head x 1 kt-chunk (256 kt), 256 threads (4 waves).
// SWAPPED QK^T: S^T = mfma(A=K rows kt, B=Q rows q) -> col q = lane&15.
// Each lane owns ONE q with 16 kt values -> in-register softmax + 2 shfl_xor.
// Q loaded DIRECTLY global->register (lane-local row, no LDS): 40 KB LDS
// -> 4 blocks/CU (was 3 at 48 KB). Q pre-scaled by 0.125 at projection.
struct AttnArgs {
  const unsigned short* Q[6];
  const unsigned short* K[6];
  const unsigned short* V[6];
};

__global__ __launch_bounds__(256) void attn_split(AttnArgs a, unsigned short* part) {
  const int z = blockIdx.z;
  const int h = blockIdx.y >> 2, ck = blockIdx.y & 3;
  const int n0 = blockIdx.x * 64;
  const unsigned short* __restrict__ Qp = a.Q[z];
  const unsigned short* __restrict__ Kp = a.K[z];
  const unsigned short* __restrict__ Vp = a.V[z];

  __shared__ char sm[40960];
  char* smKb = sm;          // 2 x 8 KB double buffer
  char* smVb = sm + 16384;  // 2 x 8 KB
  char* smP = sm + 32768;   // 8 KB (P[q][kt], wave-private rows)

  const int tid = threadIdx.x;
  const int lane = tid & 63, wid = tid >> 6;
  const int srow = tid >> 2, skb = (tid & 3) * 16;  // 64 rows x 2 16B-chunks
  const int kb0 = ck * 256;

  const int kh = (lane >> 4) * 16;
  const int qr = wid * 16 + (lane & 15);  // this lane's q row (and P/A-frag row)

  // Q fragments direct from global (row qr, bytes kh..+15 and 64+kh..+15)
  const unsigned short* qrow = Qp + (size_t)(n0 + qr) * 256 + h * 64;
  const bf16x8 qb0 = *(const bf16x8*)(qrow + (kh >> 1));
  const bf16x8 qb1 = *(const bf16x8*)(qrow + 32 + (kh >> 1));

#pragma unroll
  for (int p = 0; p < 2; ++p) {
    const int b = skb + 64 * p;
    *(float4*)(smKb + swz(srow, b)) =
        *(const float4*)(Kp + (size_t)(kb0 + srow) * 256 + h * 64 + (b >> 1));
    *(float4*)(smVb + swz(srow, b)) =
        *(const float4*)(Vp + (size_t)(h * 64 + srow) * NPTS + kb0 + (b >> 1));
  }
  __syncthreads();

  f32x4 accO[4] = {{0.f, 0.f, 0.f, 0.f}, {0.f, 0.f, 0.f, 0.f},
                   {0.f, 0.f, 0.f, 0.f}, {0.f, 0.f, 0.f, 0.f}};
  float mrun = -1e30f, lrun = 0.f;  // per-lane scalars (q = qr)

  for (int t = 0; t < 4; ++t) {
    const int co = (t & 1) << 13;
    if (t < 3) {  // prefetch next tile into other buffer
      const int no = ((t + 1) & 1) << 13;
      const int kt = kb0 + (t + 1) * 64;
#pragma unroll
      for (int p = 0; p < 2; ++p) {
        const int b = skb + 64 * p;
        *(float4*)(smKb + no + swz(srow, b)) =
            *(const float4*)(Kp + (size_t)(kt + srow) * 256 + h * 64 + (b >> 1));
        *(float4*)(smVb + no + swz(srow, b)) =
            *(const float4*)(Vp + (size_t)(h * 64 + srow) * NPTS + kt + (b >> 1));
      }
    }

    // S^T tile: s[c][r] = S[q = qr][kt = c*16 + (lane>>4)*4 + r]
    f32x4 s[4];
#pragma unroll
    for (int c = 0; c < 4; ++c) {
      const int br = c * 16 + (lane & 15);
      const bf16x8 kf0 = *(const bf16x8*)(smKb + co + swz(br, kh));
      const bf16x8 kf1 = *(const bf16x8*)(smKb + co + swz(br, 64 + kh));
      f32x4 tt = {0.f, 0.f, 0.f, 0.f};
      tt = __builtin_amdgcn_mfma_f32_16x16x32_bf16(kf0, qb0, tt, 0, 0, 0);
      tt = __builtin_amdgcn_mfma_f32_16x16x32_bf16(kf1, qb1, tt, 0, 0, 0);
      s[c] = tt;
    }

    // in-register online softmax (16 values/lane, all same q)
    float mx = s[0][0];
#pragma unroll
    for (int c = 0; c < 4; ++c)
#pragma unroll
      for (int r = 0; r < 4; ++r) mx = fmaxf(mx, s[c][r]);
    mx = fmaxf(mx, __shfl_xor(mx, 16));
    mx = fmaxf(mx, __shfl_xor(mx, 32));
    const float mn = fmaxf(mrun, mx);
    const float corr = __expf(mrun - mn);
    mrun = mn;
    float ps = 0.f;
#pragma unroll
    for (int c = 0; c < 4; ++c)
#pragma unroll
      for (int r = 0; r < 4; ++r) {
        const float e = __expf(s[c][r] - mn);
        s[c][r] = e;
        ps += e;
      }
    ps += __shfl_xor(ps, 16);
    ps += __shfl_xor(ps, 32);
    lrun = lrun * corr + ps;

    // P write: lane-local consecutive kt -> uint2, no shuffles
#pragma unroll
    for (int c = 0; c < 4; ++c) {
      uint2 u;
      u.x = pack2(s[c][0], s[c][1]);
      u.y = pack2(s[c][2], s[c][3]);
      *(uint2*)(smP + swz(qr, c * 32 + (lane >> 4) * 8)) = u;
    }

    // rescale accO rows (corr broadcast from lanes 0..15 of this wave)
#pragma unroll
    for (int r = 0; r < 4; ++r) {
      const float cr = __shfl(corr, ((lane >> 4) & 3) * 4 + r);
#pragma unroll
      for (int c = 0; c < 4; ++c) accO[c][r] *= cr;
    }

    // O += P V (A = P rows q, B = V^T rows d, k = kt); P rows wave-private
    const bf16x8 pa0 = *(const bf16x8*)(smP + swz(qr, kh));
    const bf16x8 pa1 = *(const bf16x8*)(smP + swz(qr, 64 + kh));
#pragma unroll
    for (int c = 0; c < 4; ++c) {
      const int vr = c * 16 + (lane & 15);
      const bf16x8 vb0 = *(const bf16x8*)(smVb + co + swz(vr, kh));
      const bf16x8 vb1 = *(const bf16x8*)(smVb + co + swz(vr, 64 + kh));
      accO[c] = __builtin_amdgcn_mfma_f32_16x16x32_bf16(pa0, vb0, accO[c], 0, 0, 0);
      accO[c] = __builtin_amdgcn_mfma_f32_16x16x32_bf16(pa1, vb1, accO[c], 0, 0, 0);
    }
    __syncthreads();  // buf[cur] reads done; prefetch of buf[nxt] visible
  }

  // partial record: O bf16[64][64] | m f32[64] | l f32[64]
  char* rec = (char*)part +
              (size_t)((((z * 4 + h) * 16 + blockIdx.x) * 4 + ck)) * 8704;
#pragma unroll
  for (int c = 0; c < 4; ++c)
#pragma unroll
    for (int r = 0; r < 4; ++r) {
      const float o0 = accO[c][r];
      const float o1 = __shfl_xor(o0, 1);
      if (!(lane & 1)) {
        const int row = wid * 16 + (lane >> 4) * 4 + r;
        const int col = c * 16 + (lane & 15);
        *(unsigned*)(rec + row * 128 + col * 2) = pack2(o0, o1);
      }
    }
  if (lane < 16) {
    *(float*)(rec + 8192 + (wid * 16 + lane) * 4) = mrun;
    *(float*)(rec + 8448 + (wid * 16 + lane) * 4) = lrun;
  }
}

// combine 4 kt-chunk partials -> O bf16 [n][256] head-grouped
struct CmbArgs {
  unsigned short* O[6];
};

__global__ __launch_bounds__(256) void attn_combine(CmbArgs a,
                                                    const unsigned short* part) {
  const int z = blockIdx.z, h = blockIdx.y, qb = blockIdx.x;
  const int tid = threadIdx.x;
  const int q = tid >> 2, t4 = tid & 3;
  const char* base = (const char*)part + (size_t)(((z * 4 + h) * 16 + qb) * 4) * 8704;

  float m[4], l[4];
#pragma unroll
  for (int i = 0; i < 4; ++i) {
    m[i] = *(const float*)(base + i * 8704 + 8192 + q * 4);
    l[i] = *(const float*)(base + i * 8704 + 8448 + q * 4);
  }
  const float M = fmaxf(fmaxf(m[0], m[1]), fmaxf(m[2], m[3]));
  float w[4], L = 0.f;
#pragma unroll
  for (int i = 0; i < 4; ++i) { w[i] = __expf(m[i] - M); L += w[i] * l[i]; }
  const float invL = 1.f / L;

  float o[16] = {};
#pragma unroll
  for (int i = 0; i < 4; ++i) {
    const char* Or = base + i * 8704 + q * 128 + t4 * 32;
    unsigned ua[8];
    *(uint4*)ua = *(const uint4*)Or;
    *(uint4*)(ua + 4) = *(const uint4*)(Or + 16);
#pragma unroll
    for (int j = 0; j < 8; ++j) {
      o[2 * j] += w[i] * bf2f(ua[j] & 0xFFFFu);
      o[2 * j + 1] += w[i] * bf2f(ua[j] >> 16);
    }
  }
  unsigned ou[8];
#pragma unroll
  for (int j = 0; j < 8; ++j) ou[j] = pack2(o[2 * j] * invL, o[2 * j + 1] * invL);
  unsigned short* Op = a.O[z] + (size_t)(qb * 64 + q) * 256 + h * 64 + t4 * 16;
  *(uint4*)Op = *(uint4*)ou;
  *(uint4*)(Op + 8) = *(uint4*)(ou + 4);
}

// ------------------------------------------------------ residual + LN ------
struct LnArgs {
  float* x[4];
  unsigned short* xb[4];
  const float* da[4];
  const float* db[4];
  const float* g[4];
  const float* b[4];
};

__global__ __launch_bounds__(256) void ln_rows(LnArgs a) {
  const int z = blockIdx.z;
  float* __restrict__ x = a.x[z];
  unsigned short* __restrict__ xb = a.xb[z];
  const float* __restrict__ da = a.da[z];
  const float* __restrict__ db = a.db[z];
  const float* __restrict__ g = a.g[z];
  const float* __restrict__ b = a.b[z];

  const int lane = threadIdx.x & 63, wid = threadIdx.x >> 6;
  const int n = blockIdx.x * 4 + wid;
  const size_t off = (size_t)n * 256 + lane * 4;

  float4 v = *(const float4*)(x + off);
  if (da) {
    const float4 w = *(const float4*)(da + off);
    v.x += w.x; v.y += w.y; v.z += w.z; v.w += w.w;
  }
  if (db) {
    const float4 w = *(const float4*)(db + off);
    v.x += w.x; v.y += w.y; v.z += w.z; v.w += w.w;
  }
  float s = v.x + v.y + v.z + v.w;
  float q = v.x * v.x + v.y * v.y + v.z * v.z + v.w * v.w;
#pragma unroll
  for (int o = 1; o < 64; o <<= 1) {
    s += __shfl_xor(s, o);
    q += __shfl_xor(q, o);
  }
  const float mu = s * (1.f / 256.f);
  const float var = q * (1.f / 256.f) - mu * mu;
  const float inv = rsqrtf(var + 1e-5f);
  const float4 gv = *(const float4*)(g + lane * 4);
  const float4 bv = *(const float4*)(b + lane * 4);
  float4 o;
  o.x = (v.x - mu) * inv * gv.x + bv.x;
  o.y = (v.y - mu) * inv * gv.y + bv.y;
  o.z = (v.z - mu) * inv * gv.z + bv.z;
  o.w = (v.w - mu) * inv * gv.w + bv.w;
  *(float4*)(x + off) = o;
  uint2 pk = {pack2(o.x, o.y), pack2(o.z, o.w)};
  *(uint2*)(xb + off) = pk;
}

// -------------------------------------------------------- small helpers ----
struct TrArgs {
  const float* s[4];
  float* d[4];
  unsigned short* db[4];
};
__global__ __launch_bounds__(256) void tr_init(TrArgs a) {  // [c][n] -> [n][c] + bf16
  const int z = blockIdx.z;
  const int n0 = blockIdx.x * 64, c0 = blockIdx.y * 64;
  __shared__ float T[64][65];
  const int tid = threadIdx.x;
#pragma unroll
  for (int p = 0; p < 4; ++p) {
    const int row = (tid >> 4) + 16 * p;
    const int col4 = (tid & 15) * 4;
    const float4 v = *(const float4*)(a.s[z] + (size_t)(c0 + row) * NPTS + n0 + col4);
    T[row][col4] = v.x; T[row][col4 + 1] = v.y; T[row][col4 + 2] = v.z; T[row][col4 + 3] = v.w;
  }
  __syncthreads();
#pragma unroll
  for (int p = 0; p < 4; ++p) {
    const int nr = (tid >> 4) + 16 * p;
    const int c4 = (tid & 15) * 4;
    float4 v;
    v.x = T[c4][nr]; v.y = T[c4 + 1][nr]; v.z = T[c4 + 2][nr]; v.w = T[c4 + 3][nr];
    *(float4*)(a.d[z] + (size_t)(n0 + nr) * 256 + c0 + c4) = v;
    uint2 pk = {pack2(v.x, v.y), pack2(v.z, v.w)};
    *(uint2*)(a.db[z] + (size_t)(n0 + nr) * 256 + c0 + c4) = pk;
  }
}

// weight prep. pair pi = br*5+i (layers 0..4).
// arena per pair (ushort): WQ'(64K) WK'(64K) WV'(64K) MWt(64K) W1'(256K) W2'(128K)
__global__ __launch_bounds__(256) void wp_qkv(const float* __restrict__ pw,
                                              const float* __restrict__ pb,
                                              unsigned short* __restrict__ wbf,
                                              float* __restrict__ pbias) {
  const int z = blockIdx.z;  // 45 = 15 pairs x 3 j
  const int pi = z / 3, j = z % 3;
  const int br = pi / 5, i = pi % 5;
  const float* src = pw + (((size_t)br * LNUM + i) * 3 + j) * 65536;
  unsigned short* dst = wbf + (size_t)pi * 655360 + (size_t)j * 65536;
  const int t = blockIdx.x * 256 + threadIdx.x;  // 16384
  const int mp = t >> 6, k4 = (t & 63) * 4;
  const int m = (mp & 63) * 4 + (mp >> 6);  // orig channel of head-grouped mp
  const float4 v = *(const float4*)(src + (size_t)m * 256 + k4);
  uint2 pk = {pack2(v.x, v.y), pack2(v.z, v.w)};
  *(uint2*)(dst + (size_t)mp * 256 + k4) = pk;
  if (blockIdx.x == 0) {
    const float* sb = pb + (((size_t)br * LNUM + i) * 3 + j) * 256;
    const int mb = threadIdx.x;
    pbias[(size_t)z * 256 + mb] = sb[(mb & 63) * 4 + (mb >> 6)];
  }
}

// MWt[c'][m] = merge_w[m][orig(c')]  (transposed, O-channel head-grouped rows)
__global__ __launch_bounds__(256) void wp_mwt(const float* __restrict__ mw,
                                              unsigned short* __restrict__ wbf,
                                              float* __restrict__ zb) {
  const int pi = blockIdx.z;
  const int br = pi / 5, i = pi % 5;
  const float* src = mw + ((size_t)br * LNUM + i) * 65536;
  unsigned short* dst = wbf + (size_t)pi * 655360 + 196608;
  const int t = blockIdx.x * 256 + threadIdx.x;  // 16384
  const int cp = t >> 6, m4 = (t & 63) * 4;
  const int c = (cp & 63) * 4 + (cp >> 6);  // orig col of head-grouped cp
  float v[4];
#pragma unroll
  for (int u = 0; u < 4; ++u) v[u] = src[(size_t)(m4 + u) * 256 + c];
  uint2 pk = {pack2(v[0], v[1]), pack2(v[2], v[3])};
  *(uint2*)(dst + (size_t)cp * 256 + m4) = pk;
  if (blockIdx.x == 0 && pi == 0) zb[threadIdx.x] = 0.f;
}

// W1 cast [512][512]; also emit right half (cols 256..511) to whi temp
__global__ __launch_bounds__(256) void wp_c1(const float* __restrict__ w1,
                                             unsigned short* __restrict__ wbf,
                                             unsigned short* __restrict__ whi) {
  const int pi = blockIdx.z;
  const int br = pi / 5, i = pi % 5;
  const float* src = w1 + ((size_t)br * LNUM + i) * 262144;
  unsigned short* dst = wbf + (size_t)pi * 655360 + 262144;
  const int t = blockIdx.x * 256 + threadIdx.x;  // 65536
  const float4 v = *(const float4*)(src + (size_t)t * 4);
  uint2 pk = {pack2(v.x, v.y), pack2(v.z, v.w)};
  *(uint2*)(dst + (size_t)t * 4) = pk;
  const int idx = t * 4, row = idx >> 9, col = idx & 511;
  if (col >= 256)
    *(uint2*)(whi + (size_t)pi * 131072 + (size_t)row * 256 + (col - 256)) = pk;
}

__global__ __launch_bounds__(256) void wp_c2(const float* __restrict__ w2,
                                             unsigned short* __restrict__ wbf) {
  const int pi = blockIdx.z;
  const int br = pi / 5, i = pi % 5;
  const float* src = w2 + ((size_t)br * LNUM + i) * 131072;
  unsigned short* dst = wbf + (size_t)pi * 655360 + 524288;
  const int t = blockIdx.x * 256 + threadIdx.x;  // 32768
  const float4 v = *(const float4*)(src + (size_t)t * 4);
  uint2 pk = {pack2(v.x, v.y), pack2(v.z, v.w)};
  *(uint2*)(dst + (size_t)t * 4) = pk;
}

// b1'[o] = b1[o] + sum_m W1_hi[o][m] * merge_b[m]   (fp32, per pair)
__global__ __launch_bounds__(256) void b1fold(const float* __restrict__ w1,
                                              const float* __restrict__ mb,
                                              const float* __restrict__ b1,
                                              float* __restrict__ out) {
  const int pi = blockIdx.z;
  const int br = pi / 5, i = pi % 5;
  const float* Wp = w1 + ((size_t)br * LNUM + i) * 262144;
  const float* Bp = mb + ((size_t)br * LNUM + i) * 256;
  const float* b1s = b1 + ((size_t)br * LNUM + i) * 512;
  __shared__ float mbs[256];
  mbs[threadIdx.x] = Bp[threadIdx.x];
  __syncthreads();
  for (int o = threadIdx.x; o < 512; o += 256) {
    float s = b1s[o];
    const float* Wr = Wp + (size_t)o * 512 + 256;
#pragma unroll 4
    for (int m = 0; m < 256; ++m) s = fmaf(Wr[m], mbs[m], s);
    out[(size_t)pi * 512 + o] = s;
  }
}

// ----------------------------------------------------- final (layer 5) ----
__device__ __forceinline__ float block_reduce_sum(float v) {
  __shared__ float smr[4];
  const int lane = threadIdx.x & 63, wid = threadIdx.x >> 6;
#pragma unroll
  for (int off = 32; off; off >>= 1) v += __shfl_xor(v, off);
  if (lane == 0) smr[wid] = v;
  __syncthreads();
  if (threadIdx.x == 0) v = smr[0] + smr[1] + smr[2] + smr[3];
  return v;
}

__global__ __launch_bounds__(256) void cs1(const float* __restrict__ X,
                                           float* __restrict__ part) {
  const int r0 = blockIdx.x * 64;
  float acc = 0.f;
  for (int r = 0; r < 64; ++r) acc += X[(size_t)(r0 + r) * 256 + threadIdx.x];
  part[(size_t)blockIdx.x * 256 + threadIdx.x] = acc;
}
__global__ __launch_bounds__(256) void cs2(const float* __restrict__ part,
                                           float* __restrict__ s1) {
  float acc = 0.f;
  for (int b = 0; b < 16; ++b) acc += part[(size_t)b * 256 + threadIdx.x];
  s1[threadIdx.x] = acc;
}
__global__ __launch_bounds__(256) void matvec_qbar(const float* __restrict__ Wq,
                                                   const float* __restrict__ bq,
                                                   const float* __restrict__ s1,
                                                   float* __restrict__ qbar) {
  const int d = blockIdx.x, t = threadIdx.x;
  float s = Wq[(size_t)d * 256 + t] * s1[t];
  s = block_reduce_sum(s);
  if (t == 0) qbar[d] = s + (float)NPTS * bq[d];
}
__global__ __launch_bounds__(256) void matvec_u(const float* __restrict__ Wk,
                                                const float* __restrict__ bk,
                                                const float* __restrict__ qbar,
                                                float* __restrict__ u) {
  const int c = blockIdx.x, t = threadIdx.x;
  float s = (c < 256) ? (Wk[(size_t)t * 256 + c] * qbar[t]) : (bk[t] * qbar[t]);
  s = block_reduce_sum(s);
  if (t == 0) u[c] = s;
}

// unreachable column-OR: partial[b][t] = OR over 16 rows of uint word t
__global__ __launch_bounds__(256) void ur_or(const unsigned* __restrict__ U,
                                             unsigned* __restrict__ part) {
  const int b = blockIdx.x;  // 64 blocks
  unsigned o = 0;
  for (int r = 0; r < 16; ++r) o |= U[(size_t)(b * 16 + r) * 256 + threadIdx.x];
  part[(size_t)b * 256 + threadIdx.x] = o;
}

// out[m] = mask ? -1e9 : (u . d0[m,:] + u[256]) / 32768 ; wave per m
__global__ __launch_bounds__(256) void final2(const float* __restrict__ d0,
                                              const float* __restrict__ u,
                                              const unsigned* __restrict__ part,
                                              float* __restrict__ out) {
  const int lane = threadIdx.x & 63, wid = threadIdx.x >> 6;
  const int m = blockIdx.x * 4 + wid;
  const float4 v = *(const float4*)(d0 + (size_t)m * 256 + lane * 4);
  const float4 uu = *(const float4*)(u + lane * 4);
  float s = v.x * uu.x + v.y * uu.y + v.z * uu.z + v.w * uu.w;
  unsigned f = part[(size_t)lane * 256 + (m >> 2)];
  f = (f >> ((m & 3) * 8)) & 0xFFu;
#pragma unroll
  for (int o = 32; o; o >>= 1) {
    s += __shfl_xor(s, o);
    f |= (unsigned)__shfl_xor((int)f, o);
  }
  if (lane == 0) out[m] = f ? -1e9f : (s + u[256]) * (1.f / 32768.f);
}

// ---------------------------------------------------------------- host ----
extern "C" void kernel_launch(void* const* d_in, const int* in_sizes, int n_in,
                              void* d_out, int out_size, void* d_ws, size_t ws_size,
                              hipStream_t stream) {
  const float* desc[4] = {(const float*)d_in[0], (const float*)d_in[1],
                          (const float*)d_in[2], (const float*)d_in[3]};
  const unsigned char* unreach = (const unsigned char*)d_in[5];
  const float* proj_w = (const float*)d_in[8];
  const float* proj_b = (const float*)d_in[9];
  const float* merge_w = (const float*)d_in[10];
  const float* merge_b = (const float*)d_in[11];
  const float* mlp_w1 = (const float*)d_in[12];
  const float* mlp_b1 = (const float*)d_in[13];
  const float* mlp_w2 = (const float*)d_in[14];
  const float* mlp_b2 = (const float*)d_in[15];
  const float* norm_g = (const float*)d_in[16];
  const float* norm_b = (const float*)d_in[17];
  float* out = (float*)d_out;

  float* ws = (float*)d_ws;
  // floats: dbuf 4SL | dbf 2SL | delta 6SL | wbf 4915200 | smalls 40960
  //         | attnpart 3342336 | whi 983040 | sets (4SL ushort each)
  float* dbufF[4];
  for (int t = 0; t < 4; ++t) dbufF[t] = ws + (size_t)t * SL;
  unsigned short* dbfB[4];
  for (int t = 0; t < 4; ++t) dbfB[t] = (unsigned short*)(ws + 4 * SL) + (size_t)t * SL;
  float* deltaF[6];
  for (int p = 0; p < 6; ++p) deltaF[p] = ws + 6 * SL + (size_t)p * SL;
  unsigned short* wbf = (unsigned short*)(ws + 12 * SL);
  float* pbias = ws + 12 * SL + 4915200;          // 11520
  unsigned* urpart = (unsigned*)(pbias + 11520);  // 16384 uints
  float* cspart = pbias + 11520 + 16384;          // 4096
  float* s1 = cspart + 4096;
  float* qbar = s1 + 256;
  float* uvec = qbar + 256;                       // 257 (+pad)
  float* b1prime = uvec + 260;                    // 7680
  float* zbias = b1prime + 7680;                  // 256
  unsigned short* attnpart = (unsigned short*)(ws + 12 * SL + 4915200 + 40960);
  unsigned short* whi = attnpart + (size_t)2 * 3342336;  // 15 x 512 x 256 ushorts
  const size_t base_f = 12 * SL + 4915200 + 40960 + 3342336 + 983040;
  long long avail = (long long)(ws_size / 4) - (long long)base_f;
  const size_t SET_US = 4 * SL;  // ushorts per set: Q,K,V,O
  int nsets = (int)(avail / (long long)(SET_US / 2));
  if (nsets > 6) nsets = 6;
  if (nsets < 1) nsets = 1;
  unsigned short* usBase = (unsigned short*)(ws + base_f);
  auto setQ = [&](int p) { return usBase + (size_t)p * SET_US; };
  auto setK = [&](int p) { return usBase + (size_t)p * SET_US + SL; };
  auto setV = [&](int p) { return usBase + (size_t)p * SET_US + 2 * SL; };
  auto setO = [&](int p) { return usBase + (size_t)p * SET_US + 3 * SL; };
  auto setH1 = [&](int p) { return usBase + (size_t)p * SET_US; };  // overlays Q,K

  // ---- prologue: mask OR, weight prep, merge-fold, input transpose ----
  ur_or<<<dim3(64), 256, 0, stream>>>((const unsigned*)unreach, urpart);
  wp_qkv<<<dim3(64, 1, 45), 256, 0, stream>>>(proj_w, proj_b, wbf, pbias);
  wp_mwt<<<dim3(64, 1, 15), 256, 0, stream>>>(merge_w, wbf, zbias);
  wp_c1<<<dim3(256, 1, 15), 256, 0, stream>>>(mlp_w1, wbf, whi);
  wp_c2<<<dim3(128, 1, 15), 256, 0, stream>>>(mlp_w2, wbf);
  b1fold<<<dim3(1, 1, 15), 256, 0, stream>>>(mlp_w1, merge_b, mlp_b1, b1prime);
  {  // Wf = W1_hi x MWt -> right half of W1' (cols 256..511)
    MMArgs m{};
    for (int pi = 0; pi < 15; ++pi) {
      const unsigned short* xw = whi + (size_t)pi * 131072;
      m.X[pi] = xw; m.X2[pi] = xw;
      m.W[pi] = wbf + (size_t)pi * 655360 + 196608;
      m.B[pi] = zbias;
      m.O[pi] = wbf + (size_t)pi * 655360 + 262144 + 256;
    }
    mm_bf16<false><<<dim3(8, 4, 15), 256, 0, stream>>>(m, 256, 256, 512, 0, 0, 0);
  }
  {
    TrArgs ta{};
    for (int t = 0; t < 4; ++t) { ta.s[t] = desc[t]; ta.d[t] = dbufF[t]; ta.db[t] = dbfB[t]; }
    tr_init<<<dim3(16, 4, 4), 256, 0, stream>>>(ta);
  }

  static const int selfp[4][3] = {{0, 0, 0}, {0, 1, 1}, {1, 2, 2}, {2, 3, 3}};
  static const int crossp[6][3] = {{0, 0, 1}, {0, 1, 0}, {1, 2, 1},
                                   {1, 1, 2}, {2, 0, 3}, {2, 3, 0}};

  for (int i = 0; i < 5; ++i) {
    const bool cross = (i & 1);
    const int np = cross ? 6 : 4;
    const int(*props)[3] = cross ? crossp : selfp;

    for (int p0 = 0; p0 < np; p0 += nsets) {
      const int g = (np - p0 < nsets) ? (np - p0) : nsets;

      // fused q,k,v projections (z%3==2 -> V transposed; z%3==0 -> Q x0.125)
      {
        MMArgs m{};
        for (int p = 0; p < g; ++p) {
          const int br = props[p0 + p][0], xi = props[p0 + p][1], si = props[p0 + p][2];
          const int pi = br * 5 + i;
          unsigned short* wb = wbf + (size_t)pi * 655360;
          const unsigned short* xq = dbfB[xi];
          const unsigned short* xsv = dbfB[si];
          m.X[p * 3 + 0] = xq; m.X2[p * 3 + 0] = xq; m.W[p * 3 + 0] = wb;
          m.B[p * 3 + 0] = pbias + ((size_t)pi * 3 + 0) * 256; m.O[p * 3 + 0] = setQ(p);
          m.X[p * 3 + 1] = xsv; m.X2[p * 3 + 1] = xsv; m.W[p * 3 + 1] = wb + 65536;
          m.B[p * 3 + 1] = pbias + ((size_t)pi * 3 + 1) * 256; m.O[p * 3 + 1] = setK(p);
          m.X[p * 3 + 2] = xsv; m.X2[p * 3 + 2] = xsv; m.W[p * 3 + 2] = wb + 131072;
          m.B[p * 3 + 2] = pbias + ((size_t)pi * 3 + 2) * 256; m.O[p * 3 + 2] = setV(p);
        }
        mm_bf16<false><<<dim3(16, 4, 3 * g), 256, 0, stream>>>(m, 256, 256, 256, 0, 1, 0);
      }
      // attention: split-K partials then combine
      {
        AttnArgs aa{};
        for (int p = 0; p < g; ++p) {
          aa.Q[p] = setQ(p); aa.K[p] = setK(p); aa.V[p] = setV(p);
        }
        attn_split<<<dim3(16, 16, g), 256, 0, stream>>>(aa, attnpart);
        CmbArgs cc{};
        for (int p = 0; p < g; ++p) cc.O[p] = setO(p);
        attn_combine<<<dim3(16, 4, g), 256, 0, stream>>>(cc, attnpart);
      }
      // mlp1 (relu): K=512 dual-source (x | attnO), merge folded into W1'
      {
        MMArgs m{};
        for (int p = 0; p < g; ++p) {
          const int br = props[p0 + p][0], xi = props[p0 + p][1];
          const int pi = br * 5 + i;
          m.X[p] = dbfB[xi]; m.X2[p] = setO(p);
          m.W[p] = wbf + (size_t)pi * 655360 + 262144;
          m.B[p] = b1prime + (size_t)pi * 512; m.O[p] = setH1(p);
        }
        mm_bf16<true><<<dim3(16, 8, g), 256, 0, stream>>>(m, 512, 256, 512, 0, 0, 256);
      }
      // mlp2 -> delta (fp32)
      {
        MMArgs m{};
        for (int p = 0; p < g; ++p) {
          const int br = props[p0 + p][0];
          const int pi = br * 5 + i;
          m.X[p] = setH1(p); m.X2[p] = setH1(p);
          m.W[p] = wbf + (size_t)pi * 655360 + 524288;
          m.B[p] = mlp_b2 + ((size_t)br * LNUM + i) * 256; m.O[p] = deltaF[p0 + p];
        }
        mm_bf16<false><<<dim3(16, 4, g), 256, 0, stream>>>(m, 512, 512, 256, 1, 0, 0);
      }
    }

    // residual + LN (all four descriptors)
    {
      LnArgs la{};
      for (int t = 0; t < 4; ++t) {
        la.x[t] = dbufF[t]; la.xb[t] = dbfB[t];
        const float* da = nullptr;
        const float* db2 = nullptr;
        for (int p = 0; p < np; ++p)
          if (props[p][1] == t) {
            if (!da) da = deltaF[p];
            else db2 = deltaF[p];
          }
        la.da[t] = da; la.db[t] = db2;
        la.g[t] = norm_g + ((size_t)t * LNUM + i) * 256;
        la.b[t] = norm_b + ((size_t)t * LNUM + i) * 256;
      }
      ln_rows<<<dim3(256, 1, 4), 256, 0, stream>>>(la);
    }
  }

  // ---- layer 5 shortcut ----
  const float* Wq5 = proj_w + (((size_t)0 * LNUM + 5) * 3 + 0) * 65536;
  const float* bq5 = proj_b + (((size_t)0 * LNUM + 5) * 3 + 0) * 256;
  const float* Wk5 = proj_w + (((size_t)0 * LNUM + 5) * 3 + 1) * 65536;
  const float* bk5 = proj_b + (((size_t)0 * LNUM + 5) * 3 + 1) * 256;

  cs1<<<dim3(16), 256, 0, stream>>>(dbufF[1], cspart);
  cs2<<<dim3(1), 256, 0, stream>>>(cspart, s1);
  matvec_qbar<<<dim3(256), 256, 0, stream>>>(Wq5, bq5, s1, qbar);
  matvec_u<<<dim3(257), 256, 0, stream>>>(Wk5, bk5, qbar, uvec);
  final2<<<dim3(256), 256, 0, stream>>>(dbufF[0], uvec, urpart, out);

  (void)in_sizes; (void)n_in; (void)out_size;
}

// Round 15
// 324.186 us; speedup vs baseline: 1.5726x; 1.0372x over previous
//
#include <hip/hip_runtime.h>

#define D 256
#define NPTS 1024
#define H 4
#define LNUM 6

static constexpr size_t SL = (size_t)D * NPTS;  // 262144 elements

typedef __attribute__((ext_vector_type(8))) short bf16x8;
typedef __attribute__((ext_vector_type(4))) float f32x4;

__device__ __forceinline__ unsigned f2bf(float f) {  // RNE round to bf16 bits
  unsigned u = __float_as_uint(f);
  return (u + 0x7FFFu + ((u >> 16) & 1u)) >> 16;
}
__device__ __forceinline__ unsigned pack2(float a, float b) {
  return f2bf(a) | (f2bf(b) << 16);
}
__device__ __forceinline__ float bf2f(unsigned u) {
  return __uint_as_float(u << 16);
}
// XOR swizzle for [rows][64] bf16 LDS tiles (128 B rows): conflict-optimal b128
__device__ __forceinline__ int swz(int row, int byteInRow) {
  return row * 128 + (byteInRow ^ ((row & 7) << 4));
}

// ------------------------------------------------------------- MFMA GEMM ----
// Out[n][m] = sum_k X'[n][k]*W[m][k] + bias[m], X' = X (k<split) / X2 (k>=split).
// 64x64 tile, 2-barrier K-loop (round-9 known-good; rounds 10/12 restructures
// both regressed — do not change staging or epilogue structure).
// mode 0: bf16 out [n][m]. mode 1: fp32 out. mode 2: bf16 out transposed [m][n].
// qkv=1: z%3==2 -> mode 2, os=1024 (V); z%3==0 -> output scaled by 0.125 (Q).
struct MMArgs {
  const unsigned short* X[18];
  const unsigned short* X2[18];
  const unsigned short* W[18];
  const float* B[18];
  void* O[18];
};

template <bool RELU>
__global__ __launch_bounds__(256) void mm_bf16(MMArgs a, int K, int xs, int os,
                                               int mode0, int qkv, int split) {
  const int z = blockIdx.z;
  const unsigned short* __restrict__ X = a.X[z];
  const unsigned short* __restrict__ X2 = a.X2[z];
  const unsigned short* __restrict__ W = a.W[z];
  const float* __restrict__ Bb = a.B[z];

  int mode = mode0, osz = os;
  if (qkv && (z % 3 == 2)) { mode = 2; osz = 1024; }
  const float osc = (qkv && (z % 3 == 0)) ? 0.125f : 1.0f;  // Q pre-scale 1/sqrt(dh)

  __shared__ char sm[64 * 68 * 4];  // 16 KB staging; epilogue fp32 64x68
  char* smX = sm;
  char* smW = sm + 8192;

  const int tid = threadIdx.x;
  const int n0 = blockIdx.x * 64, m0 = blockIdx.y * 64;
  const int lane = tid & 63, wid = tid >> 6;

  f32x4 acc[4] = {{0.f, 0.f, 0.f, 0.f}, {0.f, 0.f, 0.f, 0.f},
                  {0.f, 0.f, 0.f, 0.f}, {0.f, 0.f, 0.f, 0.f}};

  const int srow = tid >> 3, skb = (tid & 7) * 16;  // staging: 16B per thread
  const int ar = wid * 16 + (lane & 15);            // A row (n-local)
  const int kh = (lane >> 4) * 16;                  // k-half byte offset

  for (int k0 = 0; k0 < K; k0 += 64) {
    const int kw = k0 + (skb >> 1);  // element col
    int kx = kw;
    const unsigned short* xsrc = X;
    if (split && kx >= split) { xsrc = X2; kx -= split; }
#pragma unroll
    for (int p = 0; p < 2; ++p) {
      const int row = srow + 32 * p;
      *(float4*)(smX + swz(row, skb)) =
          *(const float4*)(xsrc + (size_t)(n0 + row) * xs + kx);
      *(float4*)(smW + swz(row, skb)) =
          *(const float4*)(W + (size_t)(m0 + row) * K + kw);
    }
    __syncthreads();
    const bf16x8 a0 = *(const bf16x8*)(smX + swz(ar, kh));
    const bf16x8 a1 = *(const bf16x8*)(smX + swz(ar, 64 + kh));
#pragma unroll
    for (int c = 0; c < 4; ++c) {
      const int br = c * 16 + (lane & 15);
      const bf16x8 b0 = *(const bf16x8*)(smW + swz(br, kh));
      const bf16x8 b1 = *(const bf16x8*)(smW + swz(br, 64 + kh));
      acc[c] = __builtin_amdgcn_mfma_f32_16x16x32_bf16(a0, b0, acc[c], 0, 0, 0);
      acc[c] = __builtin_amdgcn_mfma_f32_16x16x32_bf16(a1, b1, acc[c], 0, 0, 0);
    }
    __syncthreads();
  }

  // epilogue via LDS fp32 tile [64 n][68]
  float(*eps)[68] = (float(*)[68])sm;
#pragma unroll
  for (int c = 0; c < 4; ++c) {
    const float bs = Bb[m0 + c * 16 + (lane & 15)];
#pragma unroll
    for (int r = 0; r < 4; ++r) {
      float v = (acc[c][r] + bs) * osc;
      if (RELU) v = fmaxf(v, 0.f);
      eps[wid * 16 + (lane >> 4) * 4 + r][c * 16 + (lane & 15)] = v;
    }
  }
  __syncthreads();

#pragma unroll
  for (int p = 0; p < 2; ++p) {
    const int row = srow + 32 * p;
    const int c0 = (tid & 7) * 8;
    if (mode == 0) {
      const float4 lo = *(const float4*)&eps[row][c0];
      const float4 hi = *(const float4*)&eps[row][c0 + 4];
      uint4 u = {pack2(lo.x, lo.y), pack2(lo.z, lo.w), pack2(hi.x, hi.y), pack2(hi.z, hi.w)};
      *(uint4*)((unsigned short*)a.O[z] + (size_t)(n0 + row) * osz + m0 + c0) = u;
    } else if (mode == 1) {
      float* O = (float*)a.O[z];
      *(float4*)(O + (size_t)(n0 + row) * osz + m0 + c0) = *(const float4*)&eps[row][c0];
      *(float4*)(O + (size_t)(n0 + row) * osz + m0 + c0 + 4) = *(const float4*)&eps[row][c0 + 4];
    } else {  // transposed: out row = m, cols = n
      float v[8];
#pragma unroll
      for (int j = 0; j < 8; ++j) v[j] = eps[c0 + j][row];
      uint4 u = {pack2(v[0], v[1]), pack2(v[2], v[3]), pack2(v[4], v[5]), pack2(v[6], v[7])};
      *(uint4*)((unsigned short*)a.O[z] + (size_t)(m0 + row) * osz + n0 + c0) = u;
    }
  }
}

// ------------------------------------------------- split-K MFMA attention ----
// Block: 64 q x 1 head x 1 kt-chunk (256 kt), 256 threads (4 waves).
// SWAPPED QK^T: S^T = mfma(A=K rows kt, B=Q rows q) -> col q = lane&15.
// Each lane owns ONE q with 16 kt values -> in-register softmax + 2 shfl_xor.
// Q pre-scaled by 0.125 at projection. (r11 form: Q staged via LDS — the
// r14 global->reg Q variant measured +2.7%, reverted.)
struct AttnArgs {
  const unsigned short* Q[6];
  const unsigned short* K[6];
  const unsigned short* V[6];
};

__global__ __launch_bounds__(256) void attn_split(AttnArgs a, unsigned short* part) {
  const int z = blockIdx.z;
  const int h = blockIdx.y >> 2, ck = blockIdx.y & 3;
  const int n0 = blockIdx.x * 64;
  const unsigned short* __restrict__ Qp = a.Q[z];
  const unsigned short* __restrict__ Kp = a.K[z];
  const unsigned short* __restrict__ Vp = a.V[z];

  __shared__ char sm[49152];
  char* smQ = sm;           // 8 KB
  char* smKb = sm + 8192;   // 2 x 8 KB double buffer
  char* smVb = sm + 24576;  // 2 x 8 KB
  char* smP = sm + 40960;   // 8 KB (P[q][kt], wave-private rows)

  const int tid = threadIdx.x;
  const int lane = tid & 63, wid = tid >> 6;
  const int srow = tid >> 2, skb = (tid & 3) * 16;  // 64 rows x 2 16B-chunks
  const int kb0 = ck * 256;

#pragma unroll
  for (int p = 0; p < 2; ++p) {
    const int b = skb + 64 * p;
    *(float4*)(smQ + swz(srow, b)) =
        *(const float4*)(Qp + (size_t)(n0 + srow) * 256 + h * 64 + (b >> 1));
    *(float4*)(smKb + swz(srow, b)) =
        *(const float4*)(Kp + (size_t)(kb0 + srow) * 256 + h * 64 + (b >> 1));
    *(float4*)(smVb + swz(srow, b)) =
        *(const float4*)(Vp + (size_t)(h * 64 + srow) * NPTS + kb0 + (b >> 1));
  }
  __syncthreads();

  const int kh = (lane >> 4) * 16;
  const int qr = wid * 16 + (lane & 15);  // this lane's q row (and P/A-frag row)
  const bf16x8 qb0 = *(const bf16x8*)(smQ + swz(qr, kh));
  const bf16x8 qb1 = *(const bf16x8*)(smQ + swz(qr, 64 + kh));

  f32x4 accO[4] = {{0.f, 0.f, 0.f, 0.f}, {0.f, 0.f, 0.f, 0.f},
                   {0.f, 0.f, 0.f, 0.f}, {0.f, 0.f, 0.f, 0.f}};
  float mrun = -1e30f, lrun = 0.f;  // per-lane scalars (q = qr)

  for (int t = 0; t < 4; ++t) {
    const int co = (t & 1) << 13;
    if (t < 3) {  // prefetch next tile into other buffer
      const int no = ((t + 1) & 1) << 13;
      const int kt = kb0 + (t + 1) * 64;
#pragma unroll
      for (int p = 0; p < 2; ++p) {
        const int b = skb + 64 * p;
        *(float4*)(smKb + no + swz(srow, b)) =
            *(const float4*)(Kp + (size_t)(kt + srow) * 256 + h * 64 + (b >> 1));
        *(float4*)(smVb + no + swz(srow, b)) =
            *(const float4*)(Vp + (size_t)(h * 64 + srow) * NPTS + kt + (b >> 1));
      }
    }

    // S^T tile: s[c][r] = S[q = qr][kt = c*16 + (lane>>4)*4 + r]
    f32x4 s[4];
#pragma unroll
    for (int c = 0; c < 4; ++c) {
      const int br = c * 16 + (lane & 15);
      const bf16x8 kf0 = *(const bf16x8*)(smKb + co + swz(br, kh));
      const bf16x8 kf1 = *(const bf16x8*)(smKb + co + swz(br, 64 + kh));
      f32x4 tt = {0.f, 0.f, 0.f, 0.f};
      tt = __builtin_amdgcn_mfma_f32_16x16x32_bf16(kf0, qb0, tt, 0, 0, 0);
      tt = __builtin_amdgcn_mfma_f32_16x16x32_bf16(kf1, qb1, tt, 0, 0, 0);
      s[c] = tt;
    }

    // in-register online softmax (16 values/lane, all same q)
    float mx = s[0][0];
#pragma unroll
    for (int c = 0; c < 4; ++c)
#pragma unroll
      for (int r = 0; r < 4; ++r) mx = fmaxf(mx, s[c][r]);
    mx = fmaxf(mx, __shfl_xor(mx, 16));
    mx = fmaxf(mx, __shfl_xor(mx, 32));
    const float mn = fmaxf(mrun, mx);
    const float corr = __expf(mrun - mn);
    mrun = mn;
    float ps = 0.f;
#pragma unroll
    for (int c = 0; c < 4; ++c)
#pragma unroll
      for (int r = 0; r < 4; ++r) {
        const float e = __expf(s[c][r] - mn);
        s[c][r] = e;
        ps += e;
      }
    ps += __shfl_xor(ps, 16);
    ps += __shfl_xor(ps, 32);
    lrun = lrun * corr + ps;

    // P write: lane-local consecutive kt -> uint2, no shuffles
#pragma unroll
    for (int c = 0; c < 4; ++c) {
      uint2 u;
      u.x = pack2(s[c][0], s[c][1]);
      u.y = pack2(s[c][2], s[c][3]);
      *(uint2*)(smP + swz(qr, c * 32 + (lane >> 4) * 8)) = u;
    }

    // rescale accO rows (corr broadcast from lanes 0..15 of this wave)
#pragma unroll
    for (int r = 0; r < 4; ++r) {
      const float cr = __shfl(corr, ((lane >> 4) & 3) * 4 + r);
#pragma unroll
      for (int c = 0; c < 4; ++c) accO[c][r] *= cr;
    }

    // O += P V (A = P rows q, B = V^T rows d, k = kt); P rows wave-private
    const bf16x8 pa0 = *(const bf16x8*)(smP + swz(qr, kh));
    const bf16x8 pa1 = *(const bf16x8*)(smP + swz(qr, 64 + kh));
#pragma unroll
    for (int c = 0; c < 4; ++c) {
      const int vr = c * 16 + (lane & 15);
      const bf16x8 vb0 = *(const bf16x8*)(smVb + co + swz(vr, kh));
      const bf16x8 vb1 = *(const bf16x8*)(smVb + co + swz(vr, 64 + kh));
      accO[c] = __builtin_amdgcn_mfma_f32_16x16x32_bf16(pa0, vb0, accO[c], 0, 0, 0);
      accO[c] = __builtin_amdgcn_mfma_f32_16x16x32_bf16(pa1, vb1, accO[c], 0, 0, 0);
    }
    __syncthreads();  // buf[cur] reads done; prefetch of buf[nxt] visible
  }

  // partial record: O bf16[64][64] | m f32[64] | l f32[64]
  char* rec = (char*)part +
              (size_t)((((z * 4 + h) * 16 + blockIdx.x) * 4 + ck)) * 8704;
#pragma unroll
  for (int c = 0; c < 4; ++c)
#pragma unroll
    for (int r = 0; r < 4; ++r) {
      const float o0 = accO[c][r];
      const float o1 = __shfl_xor(o0, 1);
      if (!(lane & 1)) {
        const int row = wid * 16 + (lane >> 4) * 4 + r;
        const int col = c * 16 + (lane & 15);
        *(unsigned*)(rec + row * 128 + col * 2) = pack2(o0, o1);
      }
    }
  if (lane < 16) {
    *(float*)(rec + 8192 + (wid * 16 + lane) * 4) = mrun;
    *(float*)(rec + 8448 + (wid * 16 + lane) * 4) = lrun;
  }
}

// combine 4 kt-chunk partials -> O bf16 [n][256] head-grouped
struct CmbArgs {
  unsigned short* O[6];
};

__global__ __launch_bounds__(256) void attn_combine(CmbArgs a,
                                                    const unsigned short* part) {
  const int z = blockIdx.z, h = blockIdx.y, qb = blockIdx.x;
  const int tid = threadIdx.x;
  const int q = tid >> 2, t4 = tid & 3;
  const char* base = (const char*)part + (size_t)(((z * 4 + h) * 16 + qb) * 4) * 8704;

  float m[4], l[4];
#pragma unroll
  for (int i = 0; i < 4; ++i) {
    m[i] = *(const float*)(base + i * 8704 + 8192 + q * 4);
    l[i] = *(const float*)(base + i * 8704 + 8448 + q * 4);
  }
  const float M = fmaxf(fmaxf(m[0], m[1]), fmaxf(m[2], m[3]));
  float w[4], L = 0.f;
#pragma unroll
  for (int i = 0; i < 4; ++i) { w[i] = __expf(m[i] - M); L += w[i] * l[i]; }
  const float invL = 1.f / L;

  float o[16] = {};
#pragma unroll
  for (int i = 0; i < 4; ++i) {
    const char* Or = base + i * 8704 + q * 128 + t4 * 32;
    unsigned ua[8];
    *(uint4*)ua = *(const uint4*)Or;
    *(uint4*)(ua + 4) = *(const uint4*)(Or + 16);
#pragma unroll
    for (int j = 0; j < 8; ++j) {
      o[2 * j] += w[i] * bf2f(ua[j] & 0xFFFFu);
      o[2 * j + 1] += w[i] * bf2f(ua[j] >> 16);
    }
  }
  unsigned ou[8];
#pragma unroll
  for (int j = 0; j < 8; ++j) ou[j] = pack2(o[2 * j] * invL, o[2 * j + 1] * invL);
  unsigned short* Op = a.O[z] + (size_t)(qb * 64 + q) * 256 + h * 64 + t4 * 16;
  *(uint4*)Op = *(uint4*)ou;
  *(uint4*)(Op + 8) = *(uint4*)(ou + 4);
}

// ------------------------------------------------------ residual + LN ------
struct LnArgs {
  float* x[4];
  unsigned short* xb[4];
  const float* da[4];
  const float* db[4];
  const float* g[4];
  const float* b[4];
};

__global__ __launch_bounds__(256) void ln_rows(LnArgs a) {
  const int z = blockIdx.z;
  float* __restrict__ x = a.x[z];
  unsigned short* __restrict__ xb = a.xb[z];
  const float* __restrict__ da = a.da[z];
  const float* __restrict__ db = a.db[z];
  const float* __restrict__ g = a.g[z];
  const float* __restrict__ b = a.b[z];

  const int lane = threadIdx.x & 63, wid = threadIdx.x >> 6;
  const int n = blockIdx.x * 4 + wid;
  const size_t off = (size_t)n * 256 + lane * 4;

  float4 v = *(const float4*)(x + off);
  if (da) {
    const float4 w = *(const float4*)(da + off);
    v.x += w.x; v.y += w.y; v.z += w.z; v.w += w.w;
  }
  if (db) {
    const float4 w = *(const float4*)(db + off);
    v.x += w.x; v.y += w.y; v.z += w.z; v.w += w.w;
  }
  float s = v.x + v.y + v.z + v.w;
  float q = v.x * v.x + v.y * v.y + v.z * v.z + v.w * v.w;
#pragma unroll
  for (int o = 1; o < 64; o <<= 1) {
    s += __shfl_xor(s, o);
    q += __shfl_xor(q, o);
  }
  const float mu = s * (1.f / 256.f);
  const float var = q * (1.f / 256.f) - mu * mu;
  const float inv = rsqrtf(var + 1e-5f);
  const float4 gv = *(const float4*)(g + lane * 4);
  const float4 bv = *(const float4*)(b + lane * 4);
  float4 o;
  o.x = (v.x - mu) * inv * gv.x + bv.x;
  o.y = (v.y - mu) * inv * gv.y + bv.y;
  o.z = (v.z - mu) * inv * gv.z + bv.z;
  o.w = (v.w - mu) * inv * gv.w + bv.w;
  *(float4*)(x + off) = o;
  uint2 pk = {pack2(o.x, o.y), pack2(o.z, o.w)};
  *(uint2*)(xb + off) = pk;
}

// -------------------------------------------------------- small helpers ----
struct TrArgs {
  const float* s[4];
  float* d[4];
  unsigned short* db[4];
};
__global__ __launch_bounds__(256) void tr_init(TrArgs a) {  // [c][n] -> [n][c] + bf16
  const int z = blockIdx.z;
  const int n0 = blockIdx.x * 64, c0 = blockIdx.y * 64;
  __shared__ float T[64][65];
  const int tid = threadIdx.x;
#pragma unroll
  for (int p = 0; p < 4; ++p) {
    const int row = (tid >> 4) + 16 * p;
    const int col4 = (tid & 15) * 4;
    const float4 v = *(const float4*)(a.s[z] + (size_t)(c0 + row) * NPTS + n0 + col4);
    T[row][col4] = v.x; T[row][col4 + 1] = v.y; T[row][col4 + 2] = v.z; T[row][col4 + 3] = v.w;
  }
  __syncthreads();
#pragma unroll
  for (int p = 0; p < 4; ++p) {
    const int nr = (tid >> 4) + 16 * p;
    const int c4 = (tid & 15) * 4;
    float4 v;
    v.x = T[c4][nr]; v.y = T[c4 + 1][nr]; v.z = T[c4 + 2][nr]; v.w = T[c4 + 3][nr];
    *(float4*)(a.d[z] + (size_t)(n0 + nr) * 256 + c0 + c4) = v;
    uint2 pk = {pack2(v.x, v.y), pack2(v.z, v.w)};
    *(uint2*)(a.db[z] + (size_t)(n0 + nr) * 256 + c0 + c4) = pk;
  }
}

// weight prep. pair pi = br*5+i (layers 0..4).
// arena per pair (ushort): WQ'(64K) WK'(64K) WV'(64K) MWt(64K) W1'(256K) W2'(128K)
__global__ __launch_bounds__(256) void wp_qkv(const float* __restrict__ pw,
                                              const float* __restrict__ pb,
                                              unsigned short* __restrict__ wbf,
                                              float* __restrict__ pbias) {
  const int z = blockIdx.z;  // 45 = 15 pairs x 3 j
  const int pi = z / 3, j = z % 3;
  const int br = pi / 5, i = pi % 5;
  const float* src = pw + (((size_t)br * LNUM + i) * 3 + j) * 65536;
  unsigned short* dst = wbf + (size_t)pi * 655360 + (size_t)j * 65536;
  const int t = blockIdx.x * 256 + threadIdx.x;  // 16384
  const int mp = t >> 6, k4 = (t & 63) * 4;
  const int m = (mp & 63) * 4 + (mp >> 6);  // orig channel of head-grouped mp
  const float4 v = *(const float4*)(src + (size_t)m * 256 + k4);
  uint2 pk = {pack2(v.x, v.y), pack2(v.z, v.w)};
  *(uint2*)(dst + (size_t)mp * 256 + k4) = pk;
  if (blockIdx.x == 0) {
    const float* sb = pb + (((size_t)br * LNUM + i) * 3 + j) * 256;
    const int mb = threadIdx.x;
    pbias[(size_t)z * 256 + mb] = sb[(mb & 63) * 4 + (mb >> 6)];
  }
}

// merged: bx<64 -> MWt[c'][m] = merge_w[m][orig(c')]; bx>=64 -> W2 cast
__global__ __launch_bounds__(256) void wp_mwt_c2(const float* __restrict__ mw,
                                                 const float* __restrict__ w2,
                                                 unsigned short* __restrict__ wbf,
                                                 float* __restrict__ zb) {
  const int pi = blockIdx.z;
  const int br = pi / 5, i = pi % 5;
  if (blockIdx.x < 64) {
    const float* src = mw + ((size_t)br * LNUM + i) * 65536;
    unsigned short* dst = wbf + (size_t)pi * 655360 + 196608;
    const int t = blockIdx.x * 256 + threadIdx.x;  // 16384
    const int cp = t >> 6, m4 = (t & 63) * 4;
    const int c = (cp & 63) * 4 + (cp >> 6);  // orig col of head-grouped cp
    float v[4];
#pragma unroll
    for (int u = 0; u < 4; ++u) v[u] = src[(size_t)(m4 + u) * 256 + c];
    uint2 pk = {pack2(v[0], v[1]), pack2(v[2], v[3])};
    *(uint2*)(dst + (size_t)cp * 256 + m4) = pk;
    if (blockIdx.x == 0 && pi == 0) zb[threadIdx.x] = 0.f;
  } else {
    const float* src = w2 + ((size_t)br * LNUM + i) * 131072;
    unsigned short* dst = wbf + (size_t)pi * 655360 + 524288;
    const int t = (blockIdx.x - 64) * 256 + threadIdx.x;  // 32768
    const float4 v = *(const float4*)(src + (size_t)t * 4);
    uint2 pk = {pack2(v.x, v.y), pack2(v.z, v.w)};
    *(uint2*)(dst + (size_t)t * 4) = pk;
  }
}

// W1 cast [512][512]; also emit right half (cols 256..511) to whi temp
__global__ __launch_bounds__(256) void wp_c1(const float* __restrict__ w1,
                                             unsigned short* __restrict__ wbf,
                                             unsigned short* __restrict__ whi) {
  const int pi = blockIdx.z;
  const int br = pi / 5, i = pi % 5;
  const float* src = w1 + ((size_t)br * LNUM + i) * 262144;
  unsigned short* dst = wbf + (size_t)pi * 655360 + 262144;
  const int t = blockIdx.x * 256 + threadIdx.x;  // 65536
  const float4 v = *(const float4*)(src + (size_t)t * 4);
  uint2 pk = {pack2(v.x, v.y), pack2(v.z, v.w)};
  *(uint2*)(dst + (size_t)t * 4) = pk;
  const int idx = t * 4, row = idx >> 9, col = idx & 511;
  if (col >= 256)
    *(uint2*)(whi + (size_t)pi * 131072 + (size_t)row * 256 + (col - 256)) = pk;
}

// b1'[o] = b1[o] + sum_m W1_hi[o][m] * merge_b[m]   (fp32, per pair)
__global__ __launch_bounds__(256) void b1fold(const float* __restrict__ w1,
                                              const float* __restrict__ mb,
                                              const float* __restrict__ b1,
                                              float* __restrict__ out) {
  const int pi = blockIdx.z;
  const int br = pi / 5, i = pi % 5;
  const float* Wp = w1 + ((size_t)br * LNUM + i) * 262144;
  const float* Bp = mb + ((size_t)br * LNUM + i) * 256;
  const float* b1s = b1 + ((size_t)br * LNUM + i) * 512;
  __shared__ float mbs[256];
  mbs[threadIdx.x] = Bp[threadIdx.x];
  __syncthreads();
  for (int o = threadIdx.x; o < 512; o += 256) {
    float s = b1s[o];
    const float* Wr = Wp + (size_t)o * 512 + 256;
#pragma unroll 4
    for (int m = 0; m < 256; ++m) s = fmaf(Wr[m], mbs[m], s);
    out[(size_t)pi * 512 + o] = s;
  }
}

// ----------------------------------------------------- final (layer 5) ----
__device__ __forceinline__ float block_reduce_sum(float v) {
  __shared__ float smr[4];
  const int lane = threadIdx.x & 63, wid = threadIdx.x >> 6;
#pragma unroll
  for (int off = 32; off; off >>= 1) v += __shfl_xor(v, off);
  if (lane == 0) smr[wid] = v;
  __syncthreads();
  if (threadIdx.x == 0) v = smr[0] + smr[1] + smr[2] + smr[3];
  return v;
}

__global__ __launch_bounds__(256) void cs1(const float* __restrict__ X,
                                           float* __restrict__ part) {
  const int r0 = blockIdx.x * 64;
  float acc = 0.f;
  for (int r = 0; r < 64; ++r) acc += X[(size_t)(r0 + r) * 256 + threadIdx.x];
  part[(size_t)blockIdx.x * 256 + threadIdx.x] = acc;
}
// qbar[d] = sum_t Wq[d][t] * (sum_b part[b][t]) + N*bq[d]  (cs2 folded in)
__global__ __launch_bounds__(256) void matvec_qbar(const float* __restrict__ Wq,
                                                   const float* __restrict__ bq,
                                                   const float* __restrict__ part,
                                                   float* __restrict__ qbar) {
  const int d = blockIdx.x, t = threadIdx.x;
  float s1t = 0.f;
#pragma unroll
  for (int b = 0; b < 16; ++b) s1t += part[(size_t)b * 256 + t];
  float s = Wq[(size_t)d * 256 + t] * s1t;
  s = block_reduce_sum(s);
  if (t == 0) qbar[d] = s + (float)NPTS * bq[d];
}
__global__ __launch_bounds__(256) void matvec_u(const float* __restrict__ Wk,
                                                const float* __restrict__ bk,
                                                const float* __restrict__ qbar,
                                                float* __restrict__ u) {
  const int c = blockIdx.x, t = threadIdx.x;
  float s = (c < 256) ? (Wk[(size_t)t * 256 + c] * qbar[t]) : (bk[t] * qbar[t]);
  s = block_reduce_sum(s);
  if (t == 0) u[c] = s;
}

// unreachable column-OR: partial[b][t] = OR over 16 rows of uint word t
__global__ __launch_bounds__(256) void ur_or(const unsigned* __restrict__ U,
                                             unsigned* __restrict__ part) {
  const int b = blockIdx.x;  // 64 blocks
  unsigned o = 0;
  for (int r = 0; r < 16; ++r) o |= U[(size_t)(b * 16 + r) * 256 + threadIdx.x];
  part[(size_t)b * 256 + threadIdx.x] = o;
}

// out[m] = mask ? -1e9 : (u . d0[m,:] + u[256]) / 32768 ; wave per m
__global__ __launch_bounds__(256) void final2(const float* __restrict__ d0,
                                              const float* __restrict__ u,
                                              const unsigned* __restrict__ part,
                                              float* __restrict__ out) {
  const int lane = threadIdx.x & 63, wid = threadIdx.x >> 6;
  const int m = blockIdx.x * 4 + wid;
  const float4 v = *(const float4*)(d0 + (size_t)m * 256 + lane * 4);
  const float4 uu = *(const float4*)(u + lane * 4);
  float s = v.x * uu.x + v.y * uu.y + v.z * uu.z + v.w * uu.w;
  unsigned f = part[(size_t)lane * 256 + (m >> 2)];
  f = (f >> ((m & 3) * 8)) & 0xFFu;
#pragma unroll
  for (int o = 32; o; o >>= 1) {
    s += __shfl_xor(s, o);
    f |= (unsigned)__shfl_xor((int)f, o);
  }
  if (lane == 0) out[m] = f ? -1e9f : (s + u[256]) * (1.f / 32768.f);
}

// ---------------------------------------------------------------- host ----
extern "C" void kernel_launch(void* const* d_in, const int* in_sizes, int n_in,
                              void* d_out, int out_size, void* d_ws, size_t ws_size,
                              hipStream_t stream) {
  const float* desc[4] = {(const float*)d_in[0], (const float*)d_in[1],
                          (const float*)d_in[2], (const float*)d_in[3]};
  const unsigned char* unreach = (const unsigned char*)d_in[5];
  const float* proj_w = (const float*)d_in[8];
  const float* proj_b = (const float*)d_in[9];
  const float* merge_w = (const float*)d_in[10];
  const float* merge_b = (const float*)d_in[11];
  const float* mlp_w1 = (const float*)d_in[12];
  const float* mlp_b1 = (const float*)d_in[13];
  const float* mlp_w2 = (const float*)d_in[14];
  const float* mlp_b2 = (const float*)d_in[15];
  const float* norm_g = (const float*)d_in[16];
  const float* norm_b = (const float*)d_in[17];
  float* out = (float*)d_out;

  float* ws = (float*)d_ws;
  // floats: dbuf 4SL | dbf 2SL | delta 6SL | wbf 4915200 | smalls 40960
  //         | attnpart 3342336 | whi 983040 | sets (4SL ushort each)
  float* dbufF[4];
  for (int t = 0; t < 4; ++t) dbufF[t] = ws + (size_t)t * SL;
  unsigned short* dbfB[4];
  for (int t = 0; t < 4; ++t) dbfB[t] = (unsigned short*)(ws + 4 * SL) + (size_t)t * SL;
  float* deltaF[6];
  for (int p = 0; p < 6; ++p) deltaF[p] = ws + 6 * SL + (size_t)p * SL;
  unsigned short* wbf = (unsigned short*)(ws + 12 * SL);
  float* pbias = ws + 12 * SL + 4915200;          // 11520
  unsigned* urpart = (unsigned*)(pbias + 11520);  // 16384 uints
  float* cspart = pbias + 11520 + 16384;          // 4096
  float* s1 = cspart + 4096;
  float* qbar = s1 + 256;
  float* uvec = qbar + 256;                       // 257 (+pad)
  float* b1prime = uvec + 260;                    // 7680
  float* zbias = b1prime + 7680;                  // 256
  unsigned short* attnpart = (unsigned short*)(ws + 12 * SL + 4915200 + 40960);
  unsigned short* whi = attnpart + (size_t)2 * 3342336;  // 15 x 512 x 256 ushorts
  const size_t base_f = 12 * SL + 4915200 + 40960 + 3342336 + 983040;
  long long avail = (long long)(ws_size / 4) - (long long)base_f;
  const size_t SET_US = 4 * SL;  // ushorts per set: Q,K,V,O
  int nsets = (int)(avail / (long long)(SET_US / 2));
  if (nsets > 6) nsets = 6;
  if (nsets < 1) nsets = 1;
  unsigned short* usBase = (unsigned short*)(ws + base_f);
  auto setQ = [&](int p) { return usBase + (size_t)p * SET_US; };
  auto setK = [&](int p) { return usBase + (size_t)p * SET_US + SL; };
  auto setV = [&](int p) { return usBase + (size_t)p * SET_US + 2 * SL; };
  auto setO = [&](int p) { return usBase + (size_t)p * SET_US + 3 * SL; };
  auto setH1 = [&](int p) { return usBase + (size_t)p * SET_US; };  // overlays Q,K

  // ---- prologue: mask OR, weight prep, merge-fold, input transpose ----
  ur_or<<<dim3(64), 256, 0, stream>>>((const unsigned*)unreach, urpart);
  wp_qkv<<<dim3(64, 1, 45), 256, 0, stream>>>(proj_w, proj_b, wbf, pbias);
  wp_mwt_c2<<<dim3(192, 1, 15), 256, 0, stream>>>(merge_w, mlp_w2, wbf, zbias);
  wp_c1<<<dim3(256, 1, 15), 256, 0, stream>>>(mlp_w1, wbf, whi);
  b1fold<<<dim3(1, 1, 15), 256, 0, stream>>>(mlp_w1, merge_b, mlp_b1, b1prime);
  {  // Wf = W1_hi x MWt -> right half of W1' (cols 256..511)
    MMArgs m{};
    for (int pi = 0; pi < 15; ++pi) {
      const unsigned short* xw = whi + (size_t)pi * 131072;
      m.X[pi] = xw; m.X2[pi] = xw;
      m.W[pi] = wbf + (size_t)pi * 655360 + 196608;
      m.B[pi] = zbias;
      m.O[pi] = wbf + (size_t)pi * 655360 + 262144 + 256;
    }
    mm_bf16<false><<<dim3(8, 4, 15), 256, 0, stream>>>(m, 256, 256, 512, 0, 0, 0);
  }
  {
    TrArgs ta{};
    for (int t = 0; t < 4; ++t) { ta.s[t] = desc[t]; ta.d[t] = dbufF[t]; ta.db[t] = dbfB[t]; }
    tr_init<<<dim3(16, 4, 4), 256, 0, stream>>>(ta);
  }

  static const int selfp[4][3] = {{0, 0, 0}, {0, 1, 1}, {1, 2, 2}, {2, 3, 3}};
  static const int crossp[6][3] = {{0, 0, 1}, {0, 1, 0}, {1, 2, 1},
                                   {1, 1, 2}, {2, 0, 3}, {2, 3, 0}};

  for (int i = 0; i < 5; ++i) {
    const bool cross = (i & 1);
    const int np = cross ? 6 : 4;
    const int(*props)[3] = cross ? crossp : selfp;

    for (int p0 = 0; p0 < np; p0 += nsets) {
      const int g = (np - p0 < nsets) ? (np - p0) : nsets;

      // fused q,k,v projections (z%3==2 -> V transposed; z%3==0 -> Q x0.125)
      {
        MMArgs m{};
        for (int p = 0; p < g; ++p) {
          const int br = props[p0 + p][0], xi = props[p0 + p][1], si = props[p0 + p][2];
          const int pi = br * 5 + i;
          unsigned short* wb = wbf + (size_t)pi * 655360;
          const unsigned short* xq = dbfB[xi];
          const unsigned short* xsv = dbfB[si];
          m.X[p * 3 + 0] = xq; m.X2[p * 3 + 0] = xq; m.W[p * 3 + 0] = wb;
          m.B[p * 3 + 0] = pbias + ((size_t)pi * 3 + 0) * 256; m.O[p * 3 + 0] = setQ(p);
          m.X[p * 3 + 1] = xsv; m.X2[p * 3 + 1] = xsv; m.W[p * 3 + 1] = wb + 65536;
          m.B[p * 3 + 1] = pbias + ((size_t)pi * 3 + 1) * 256; m.O[p * 3 + 1] = setK(p);
          m.X[p * 3 + 2] = xsv; m.X2[p * 3 + 2] = xsv; m.W[p * 3 + 2] = wb + 131072;
          m.B[p * 3 + 2] = pbias + ((size_t)pi * 3 + 2) * 256; m.O[p * 3 + 2] = setV(p);
        }
        mm_bf16<false><<<dim3(16, 4, 3 * g), 256, 0, stream>>>(m, 256, 256, 256, 0, 1, 0);
      }
      // attention: split-K partials then combine
      {
        AttnArgs aa{};
        for (int p = 0; p < g; ++p) {
          aa.Q[p] = setQ(p); aa.K[p] = setK(p); aa.V[p] = setV(p);
        }
        attn_split<<<dim3(16, 16, g), 256, 0, stream>>>(aa, attnpart);
        CmbArgs cc{};
        for (int p = 0; p < g; ++p) cc.O[p] = setO(p);
        attn_combine<<<dim3(16, 4, g), 256, 0, stream>>>(cc, attnpart);
      }
      // mlp1 (relu): K=512 dual-source (x | attnO), merge folded into W1'
      {
        MMArgs m{};
        for (int p = 0; p < g; ++p) {
          const int br = props[p0 + p][0], xi = props[p0 + p][1];
          const int pi = br * 5 + i;
          m.X[p] = dbfB[xi]; m.X2[p] = setO(p);
          m.W[p] = wbf + (size_t)pi * 655360 + 262144;
          m.B[p] = b1prime + (size_t)pi * 512; m.O[p] = setH1(p);
        }
        mm_bf16<true><<<dim3(16, 8, g), 256, 0, stream>>>(m, 512, 256, 512, 0, 0, 256);
      }
      // mlp2 -> delta (fp32)
      {
        MMArgs m{};
        for (int p = 0; p < g; ++p) {
          const int br = props[p0 + p][0];
          const int pi = br * 5 + i;
          m.X[p] = setH1(p); m.X2[p] = setH1(p);
          m.W[p] = wbf + (size_t)pi * 655360 + 524288;
          m.B[p] = mlp_b2 + ((size_t)br * LNUM + i) * 256; m.O[p] = deltaF[p0 + p];
        }
        mm_bf16<false><<<dim3(16, 4, g), 256, 0, stream>>>(m, 512, 512, 256, 1, 0, 0);
      }
    }

    // residual + LN (all four descriptors)
    {
      LnArgs la{};
      for (int t = 0; t < 4; ++t) {
        la.x[t] = dbufF[t]; la.xb[t] = dbfB[t];
        const float* da = nullptr;
        const float* db2 = nullptr;
        for (int p = 0; p < np; ++p)
          if (props[p][1] == t) {
            if (!da) da = deltaF[p];
            else db2 = deltaF[p];
          }
        la.da[t] = da; la.db[t] = db2;
        la.g[t] = norm_g + ((size_t)t * LNUM + i) * 256;
        la.b[t] = norm_b + ((size_t)t * LNUM + i) * 256;
      }
      ln_rows<<<dim3(256, 1, 4), 256, 0, stream>>>(la);
    }
  }

  // ---- layer 5 shortcut ----
  const float* Wq5 = proj_w + (((size_t)0 * LNUM + 5) * 3 + 0) * 65536;
  const float* bq5 = proj_b + (((size_t)0 * LNUM + 5) * 3 + 0) * 256;
  const float* Wk5 = proj_w + (((size_t)0 * LNUM + 5) * 3 + 1) * 65536;
  const float* bk5 = proj_b + (((size_t)0 * LNUM + 5) * 3 + 1) * 256;

  cs1<<<dim3(16), 256, 0, stream>>>(dbufF[1], cspart);
  matvec_qbar<<<dim3(256), 256, 0, stream>>>(Wq5, bq5, cspart, qbar);
  matvec_u<<<dim3(257), 256, 0, stream>>>(Wk5, bk5, qbar, uvec);
  final2<<<dim3(256), 256, 0, stream>>>(dbufF[0], uvec, urpart, out);

  (void)in_sizes; (void)n_in; (void)out_size; (void)s1;
}